// Round 2
// baseline (1222.699 us; speedup 1.0000x reference)
//
#include <hip/hip_runtime.h>
#include <hip/hip_bf16.h>

#define N_NODES 50000
#define N_EDGES 800000
#define N_GRAPHS 64
#define IN_C 128
#define HID 96
#define SLICES 8
#define EDGES_PER_BLOCK 4

__global__ void deg_kernel(const int* __restrict__ dst, float* __restrict__ deg, int nE) {
    int e = blockIdx.x * blockDim.x + threadIdx.x;
    if (e < nE) atomicAdd(&deg[dst[e]], 1.0f);
}

__global__ void dinv_kernel(float* __restrict__ deg, int n) {
    int i = blockIdx.x * blockDim.x + threadIdx.x;
    if (i < n) deg[i] = rsqrtf(deg[i] + 1.0f);
}

__global__ void range_kernel(const int* __restrict__ batch, int* __restrict__ gstart,
                             int* __restrict__ gend, int n) {
    int i = blockIdx.x * blockDim.x + threadIdx.x;
    if (i < n) {
        int g = batch[i];
        atomicMin(&gstart[g], i);
        atomicMax(&gend[g], i);
    }
}

// H[n][c] = sum_k X[n][k] * W[k][c]   (one block per node, blockDim == C == 96)
__global__ void gemm_kernel(const float* __restrict__ X, const float* __restrict__ W,
                            float* __restrict__ H, int K, int C) {
    __shared__ float xs[IN_C];
    int n = blockIdx.x;
    for (int k = threadIdx.x; k < K; k += blockDim.x)
        xs[k] = X[(size_t)n * K + k];
    __syncthreads();
    int c = threadIdx.x;
    float acc = 0.f;
    for (int k = 0; k < K; ++k)
        acc = fmaf(xs[k], W[k * C + c], acc);
    H[(size_t)n * C + c] = acc;
}

// AGG[dst] += H[src] * dinv[src]*dinv[dst]   (EDGES_PER_BLOCK edges per block)
__global__ void edge_kernel(const int* __restrict__ src, const int* __restrict__ dst,
                            const float* __restrict__ dinv, const float* __restrict__ H,
                            float* __restrict__ AGG, int nE) {
    int e = blockIdx.x * EDGES_PER_BLOCK + threadIdx.x / HID;
    if (e >= nE) return;
    int c = threadIdx.x % HID;
    int s = src[e], d = dst[e];
    float nrm = dinv[s] * dinv[d];
    atomicAdd(&AGG[(size_t)d * HID + c], H[(size_t)s * HID + c] * nrm);
}

// AGG[n] += H[n]*dinv[n]^2 + b
__global__ void self_bias_kernel(const float* __restrict__ H, const float* __restrict__ dinv,
                                 const float* __restrict__ b, float* __restrict__ AGG) {
    int n = blockIdx.x, c = threadIdx.x;
    float di = dinv[n];
    AGG[(size_t)n * HID + c] += H[(size_t)n * HID + c] * di * di + b[c];
}

// Per-graph partial sums (grid: N_GRAPHS x SLICES, blockDim == HID)
__global__ void gn_partial(const float* __restrict__ X, const int* __restrict__ gstart,
                           const int* __restrict__ gend, float* __restrict__ gSum,
                           float* __restrict__ gSq) {
    int g = blockIdx.x, sl = blockIdx.y, c = threadIdx.x;
    int s = gstart[g], e = gend[g];
    if (s > e) return;
    int cnt = e - s + 1;
    int per = (cnt + SLICES - 1) / SLICES;
    int n0 = s + sl * per;
    int n1 = min(n0 + per - 1, e);
    if (n0 > n1) return;
    float sum = 0.f, sq = 0.f;
    for (int n = n0; n <= n1; ++n) {
        float v = X[(size_t)n * HID + c];
        sum += v;
        sq = fmaf(v, v, sq);
    }
    atomicAdd(&gSum[g * HID + c], sum);
    atomicAdd(&gSq[g * HID + c], sq);
}

// A = w*rsqrt(var+eps);  B = b - alpha*mean*A
__global__ void gn_finalize(const float* __restrict__ gSum, const float* __restrict__ gSq,
                            const int* __restrict__ gstart, const int* __restrict__ gend,
                            const float* __restrict__ w, const float* __restrict__ b,
                            const float* __restrict__ a, float* __restrict__ gA,
                            float* __restrict__ gB) {
    int g = blockIdx.x, c = threadIdx.x;
    int s = gstart[g], e = gend[g];
    float A = 0.f, B = 0.f;
    if (s <= e) {
        float cnt = (float)(e - s + 1);
        float mean = gSum[g * HID + c] / cnt;
        float alpha = a[c];
        float var = gSq[g * HID + c] / cnt - (2.f * alpha - alpha * alpha) * mean * mean;
        var = fmaxf(var, 0.f);
        float rs = rsqrtf(var + 1e-5f);
        A = w[c] * rs;
        B = b[c] - alpha * mean * A;
    }
    gA[g * HID + c] = A;
    gB[g * HID + c] = B;
}

// y = relu(x*A[g] + B[g])  (safe in-place: element-wise)
__global__ void gn_apply(const float* __restrict__ X, const int* __restrict__ batch,
                         const float* __restrict__ gA, const float* __restrict__ gB,
                         float* __restrict__ Y) {
    int n = blockIdx.x, c = threadIdx.x;
    int g = batch[n];
    float v = fmaf(X[(size_t)n * HID + c], gA[g * HID + c], gB[g * HID + c]);
    Y[(size_t)n * HID + c] = fmaxf(v, 0.f);
}

extern "C" void kernel_launch(void* const* d_in, const int* in_sizes, int n_in,
                              void* d_out, int out_size, void* d_ws, size_t ws_size,
                              hipStream_t stream) {
    const float* x     = (const float*)d_in[0];
    const int*   edge  = (const int*)d_in[1];
    const int*   batch = (const int*)d_in[2];
    const float* W1    = (const float*)d_in[3];
    const float* b1    = (const float*)d_in[4];
    const float* gn1_w = (const float*)d_in[5];
    const float* gn1_b = (const float*)d_in[6];
    const float* gn1_a = (const float*)d_in[7];
    const float* W2    = (const float*)d_in[8];
    const float* b2    = (const float*)d_in[9];
    const float* gn2_w = (const float*)d_in[10];
    const float* gn2_b = (const float*)d_in[11];
    const float* gn2_a = (const float*)d_in[12];
    float* out = (float*)d_out;

    const int* srcv = edge;
    const int* dstv = edge + N_EDGES;

    float* ws   = (float*)d_ws;
    float* dinv = ws;                              // 50048
    float* bufA = ws + 50048;                      // 4,800,000  (H)
    float* bufB = bufA + (size_t)N_NODES * HID;    // 4,800,000  (agg1 / relu1)
    float* gSum = bufB + (size_t)N_NODES * HID;    // 6144
    float* gSq  = gSum + N_GRAPHS * HID;           // 6144
    float* gA   = gSq + N_GRAPHS * HID;            // 6144
    float* gB   = gA + N_GRAPHS * HID;             // 6144
    int*   gstart = (int*)(gB + N_GRAPHS * HID);   // 64
    int*   gend   = gstart + N_GRAPHS;             // 64

    // degree -> dinv (shared by both layers)
    hipMemsetAsync(dinv, 0, N_NODES * sizeof(float), stream);
    deg_kernel<<<(N_EDGES + 255) / 256, 256, 0, stream>>>(dstv, dinv, N_EDGES);
    dinv_kernel<<<(N_NODES + 255) / 256, 256, 0, stream>>>(dinv, N_NODES);

    // graph node ranges (batch is sorted)
    hipMemsetAsync(gstart, 0x7F, N_GRAPHS * sizeof(int), stream);
    hipMemsetAsync(gend, 0, N_GRAPHS * sizeof(int), stream);
    range_kernel<<<(N_NODES + 255) / 256, 256, 0, stream>>>(batch, gstart, gend, N_NODES);

    const int edgeBlocks = (N_EDGES + EDGES_PER_BLOCK - 1) / EDGES_PER_BLOCK;

    // ---------- layer 1 ----------
    gemm_kernel<<<N_NODES, HID, 0, stream>>>(x, W1, bufA, IN_C, HID);
    hipMemsetAsync(bufB, 0, (size_t)N_NODES * HID * sizeof(float), stream);
    edge_kernel<<<edgeBlocks, HID * EDGES_PER_BLOCK, 0, stream>>>(srcv, dstv, dinv, bufA, bufB, N_EDGES);
    self_bias_kernel<<<N_NODES, HID, 0, stream>>>(bufA, dinv, b1, bufB);
    hipMemsetAsync(gSum, 0, 2 * N_GRAPHS * HID * sizeof(float), stream);
    gn_partial<<<dim3(N_GRAPHS, SLICES), HID, 0, stream>>>(bufB, gstart, gend, gSum, gSq);
    gn_finalize<<<N_GRAPHS, HID, 0, stream>>>(gSum, gSq, gstart, gend, gn1_w, gn1_b, gn1_a, gA, gB);
    gn_apply<<<N_NODES, HID, 0, stream>>>(bufB, batch, gA, gB, bufB);  // in-place

    // ---------- layer 2 ----------
    gemm_kernel<<<N_NODES, HID, 0, stream>>>(bufB, W2, bufA, HID, HID);
    hipMemsetAsync(out, 0, (size_t)N_NODES * HID * sizeof(float), stream);
    edge_kernel<<<edgeBlocks, HID * EDGES_PER_BLOCK, 0, stream>>>(srcv, dstv, dinv, bufA, out, N_EDGES);
    self_bias_kernel<<<N_NODES, HID, 0, stream>>>(bufA, dinv, b2, out);
    hipMemsetAsync(gSum, 0, 2 * N_GRAPHS * HID * sizeof(float), stream);
    gn_partial<<<dim3(N_GRAPHS, SLICES), HID, 0, stream>>>(out, gstart, gend, gSum, gSq);
    gn_finalize<<<N_GRAPHS, HID, 0, stream>>>(gSum, gSq, gstart, gend, gn2_w, gn2_b, gn2_a, gA, gB);
    gn_apply<<<N_NODES, HID, 0, stream>>>(out, batch, gA, gB, out);  // in-place
}

// Round 3
// 911.267 us; speedup vs baseline: 1.3418x; 1.3418x over previous
//
#include <hip/hip_runtime.h>
#include <hip/hip_bf16.h>

#define N_NODES 50000
#define N_EDGES 800000
#define N_GRAPHS 64
#define IN_C 128
#define HID 96
#define SLICES 8
#define EDGES_PER_BLOCK 4

__global__ void deg_kernel(const int* __restrict__ dst, float* __restrict__ deg, int nE) {
    int e = blockIdx.x * blockDim.x + threadIdx.x;
    if (e < nE) atomicAdd(&deg[dst[e]], 1.0f);
}

__global__ void dinv_kernel(float* __restrict__ deg, int n) {
    int i = blockIdx.x * blockDim.x + threadIdx.x;
    if (i < n) deg[i] = rsqrtf(deg[i] + 1.0f);
}

// batch is sorted: node i starts graph batch[i] iff i==0 || batch[i]!=batch[i-1]
__global__ void bounds_kernel(const int* __restrict__ batch, int* __restrict__ gstart,
                              int* __restrict__ gend, int n) {
    int i = blockIdx.x * blockDim.x + threadIdx.x;
    if (i >= n) return;
    int g = batch[i];
    if (i == 0) {
        gstart[g] = 0;
    } else {
        int gp = batch[i - 1];
        if (gp != g) { gstart[g] = i; gend[gp] = i - 1; }
    }
    if (i == n - 1) gend[g] = n - 1;
}

// enorm[e] = dinv[src]*dinv[dst]  (computed once, used by both layers)
__global__ void norm_kernel(const int* __restrict__ src, const int* __restrict__ dst,
                            const float* __restrict__ dinv, float* __restrict__ enorm, int nE) {
    int e = blockIdx.x * blockDim.x + threadIdx.x;
    if (e < nE) enorm[e] = dinv[src[e]] * dinv[dst[e]];
}

// H[n][c] = sum_k X[n][k] * W[k][c]   (one block per node, blockDim == C == 96)
__global__ void gemm_kernel(const float* __restrict__ X, const float* __restrict__ W,
                            float* __restrict__ H, int K, int C) {
    __shared__ float xs[IN_C];
    int n = blockIdx.x;
    for (int k = threadIdx.x; k < K; k += blockDim.x)
        xs[k] = X[(size_t)n * K + k];
    __syncthreads();
    int c = threadIdx.x;
    float acc = 0.f;
    for (int k = 0; k < K; ++k)
        acc = fmaf(xs[k], W[k * C + c], acc);
    H[(size_t)n * C + c] = acc;
}

// AGG[dst] += H[src] * enorm[e]   (EDGES_PER_BLOCK edges per block)
__global__ void edge_kernel(const int* __restrict__ src, const int* __restrict__ dst,
                            const float* __restrict__ enorm, const float* __restrict__ H,
                            float* __restrict__ AGG, int nE) {
    int e = blockIdx.x * EDGES_PER_BLOCK + threadIdx.x / HID;
    if (e >= nE) return;
    int c = threadIdx.x % HID;
    int s = src[e], d = dst[e];
    float nrm = enorm[e];
    atomicAdd(&AGG[(size_t)d * HID + c], H[(size_t)s * HID + c] * nrm);
}

// AGG[n] += H[n]*dinv[n]^2 + b
__global__ void self_bias_kernel(const float* __restrict__ H, const float* __restrict__ dinv,
                                 const float* __restrict__ b, float* __restrict__ AGG) {
    int n = blockIdx.x, c = threadIdx.x;
    float di = dinv[n];
    AGG[(size_t)n * HID + c] += H[(size_t)n * HID + c] * di * di + b[c];
}

// Per-graph partial sums (grid: N_GRAPHS x SLICES, blockDim == HID)
__global__ void gn_partial(const float* __restrict__ X, const int* __restrict__ gstart,
                           const int* __restrict__ gend, float* __restrict__ gSum,
                           float* __restrict__ gSq) {
    int g = blockIdx.x, sl = blockIdx.y, c = threadIdx.x;
    int s = gstart[g], e = gend[g];
    if (s > e) return;
    int cnt = e - s + 1;
    int per = (cnt + SLICES - 1) / SLICES;
    int n0 = s + sl * per;
    int n1 = min(n0 + per - 1, e);
    if (n0 > n1) return;
    float sum = 0.f, sq = 0.f;
    for (int n = n0; n <= n1; ++n) {
        float v = X[(size_t)n * HID + c];
        sum += v;
        sq = fmaf(v, v, sq);
    }
    atomicAdd(&gSum[g * HID + c], sum);
    atomicAdd(&gSq[g * HID + c], sq);
}

// A = w*rsqrt(var+eps);  B = b - alpha*mean*A
__global__ void gn_finalize(const float* __restrict__ gSum, const float* __restrict__ gSq,
                            const int* __restrict__ gstart, const int* __restrict__ gend,
                            const float* __restrict__ w, const float* __restrict__ b,
                            const float* __restrict__ a, float* __restrict__ gA,
                            float* __restrict__ gB) {
    int g = blockIdx.x, c = threadIdx.x;
    int s = gstart[g], e = gend[g];
    float A = 0.f, B = 0.f;
    if (s <= e) {
        float cnt = (float)(e - s + 1);
        float mean = gSum[g * HID + c] / cnt;
        float alpha = a[c];
        float var = gSq[g * HID + c] / cnt - (2.f * alpha - alpha * alpha) * mean * mean;
        var = fmaxf(var, 0.f);
        float rs = rsqrtf(var + 1e-5f);
        A = w[c] * rs;
        B = b[c] - alpha * mean * A;
    }
    gA[g * HID + c] = A;
    gB[g * HID + c] = B;
}

// y = relu(x*A[g] + B[g])  (safe in-place: element-wise)
__global__ void gn_apply(const float* __restrict__ X, const int* __restrict__ batch,
                         const float* __restrict__ gA, const float* __restrict__ gB,
                         float* __restrict__ Y) {
    int n = blockIdx.x, c = threadIdx.x;
    int g = batch[n];
    float v = fmaf(X[(size_t)n * HID + c], gA[g * HID + c], gB[g * HID + c]);
    Y[(size_t)n * HID + c] = fmaxf(v, 0.f);
}

extern "C" void kernel_launch(void* const* d_in, const int* in_sizes, int n_in,
                              void* d_out, int out_size, void* d_ws, size_t ws_size,
                              hipStream_t stream) {
    const float* x     = (const float*)d_in[0];
    const int*   edge  = (const int*)d_in[1];
    const int*   batch = (const int*)d_in[2];
    const float* W1    = (const float*)d_in[3];
    const float* b1    = (const float*)d_in[4];
    const float* gn1_w = (const float*)d_in[5];
    const float* gn1_b = (const float*)d_in[6];
    const float* gn1_a = (const float*)d_in[7];
    const float* W2    = (const float*)d_in[8];
    const float* b2    = (const float*)d_in[9];
    const float* gn2_w = (const float*)d_in[10];
    const float* gn2_b = (const float*)d_in[11];
    const float* gn2_a = (const float*)d_in[12];
    float* out = (float*)d_out;

    const int* srcv = edge;
    const int* dstv = edge + N_EDGES;

    float* ws    = (float*)d_ws;
    float* dinv  = ws;                              // 50048
    float* bufA  = ws + 50048;                      // 4,800,000  (H)
    float* bufB  = bufA + (size_t)N_NODES * HID;    // 4,800,000  (agg1 / relu1)
    float* enorm = bufB + (size_t)N_NODES * HID;    // 800,000
    float* gSum  = enorm + N_EDGES;                 // 6144
    float* gSq   = gSum + N_GRAPHS * HID;           // 6144
    float* gA    = gSq + N_GRAPHS * HID;            // 6144
    float* gB    = gA + N_GRAPHS * HID;             // 6144
    int*   gstart = (int*)(gB + N_GRAPHS * HID);    // 64
    int*   gend   = gstart + N_GRAPHS;              // 64

    // degree -> dinv (shared by both layers)
    hipMemsetAsync(dinv, 0, N_NODES * sizeof(float), stream);
    deg_kernel<<<(N_EDGES + 255) / 256, 256, 0, stream>>>(dstv, dinv, N_EDGES);
    dinv_kernel<<<(N_NODES + 255) / 256, 256, 0, stream>>>(dinv, N_NODES);

    // graph node ranges (batch is sorted; no atomics)
    hipMemsetAsync(gstart, 0x7F, N_GRAPHS * sizeof(int), stream);
    hipMemsetAsync(gend, 0, N_GRAPHS * sizeof(int), stream);
    bounds_kernel<<<(N_NODES + 255) / 256, 256, 0, stream>>>(batch, gstart, gend, N_NODES);

    // per-edge norm, used by both layers
    norm_kernel<<<(N_EDGES + 255) / 256, 256, 0, stream>>>(srcv, dstv, dinv, enorm, N_EDGES);

    const int edgeBlocks = (N_EDGES + EDGES_PER_BLOCK - 1) / EDGES_PER_BLOCK;

    // ---------- layer 1 ----------
    gemm_kernel<<<N_NODES, HID, 0, stream>>>(x, W1, bufA, IN_C, HID);
    hipMemsetAsync(bufB, 0, (size_t)N_NODES * HID * sizeof(float), stream);
    edge_kernel<<<edgeBlocks, HID * EDGES_PER_BLOCK, 0, stream>>>(srcv, dstv, enorm, bufA, bufB, N_EDGES);
    self_bias_kernel<<<N_NODES, HID, 0, stream>>>(bufA, dinv, b1, bufB);
    hipMemsetAsync(gSum, 0, 2 * N_GRAPHS * HID * sizeof(float), stream);
    gn_partial<<<dim3(N_GRAPHS, SLICES), HID, 0, stream>>>(bufB, gstart, gend, gSum, gSq);
    gn_finalize<<<N_GRAPHS, HID, 0, stream>>>(gSum, gSq, gstart, gend, gn1_w, gn1_b, gn1_a, gA, gB);
    gn_apply<<<N_NODES, HID, 0, stream>>>(bufB, batch, gA, gB, bufB);  // in-place

    // ---------- layer 2 ----------
    gemm_kernel<<<N_NODES, HID, 0, stream>>>(bufB, W2, bufA, HID, HID);
    hipMemsetAsync(out, 0, (size_t)N_NODES * HID * sizeof(float), stream);
    edge_kernel<<<edgeBlocks, HID * EDGES_PER_BLOCK, 0, stream>>>(srcv, dstv, enorm, bufA, out, N_EDGES);
    self_bias_kernel<<<N_NODES, HID, 0, stream>>>(bufA, dinv, b2, out);
    hipMemsetAsync(gSum, 0, 2 * N_GRAPHS * HID * sizeof(float), stream);
    gn_partial<<<dim3(N_GRAPHS, SLICES), HID, 0, stream>>>(out, gstart, gend, gSum, gSq);
    gn_finalize<<<N_GRAPHS, HID, 0, stream>>>(gSum, gSq, gstart, gend, gn2_w, gn2_b, gn2_a, gA, gB);
    gn_apply<<<N_NODES, HID, 0, stream>>>(out, batch, gA, gB, out);  // in-place
}

// Round 4
// 555.154 us; speedup vs baseline: 2.2024x; 1.6415x over previous
//
#include <hip/hip_runtime.h>
#include <hip/hip_bf16.h>

#define N_NODES 50000
#define N_EDGES 800000
#define N_GRAPHS 64
#define IN_C 128
#define HID 96
#define SLICES 8
#define SCAN_NB ((N_NODES + 255) / 256)   // 196

// ---------- preprocessing ----------

__global__ void deg_kernel(const int* __restrict__ dst, int* __restrict__ deg, int nE) {
    int e = blockIdx.x * blockDim.x + threadIdx.x;
    if (e < nE) atomicAdd(&deg[dst[e]], 1);
}

__global__ void dinv_kernel(const int* __restrict__ deg, float* __restrict__ dinv, int n) {
    int i = blockIdx.x * blockDim.x + threadIdx.x;
    if (i < n) dinv[i] = rsqrtf((float)deg[i] + 1.0f);
}

// batch is sorted: node i starts graph batch[i] iff i==0 || batch[i]!=batch[i-1]
__global__ void bounds_kernel(const int* __restrict__ batch, int* __restrict__ gstart,
                              int* __restrict__ gend, int n) {
    int i = blockIdx.x * blockDim.x + threadIdx.x;
    if (i >= n) return;
    int g = batch[i];
    if (i == 0) {
        gstart[g] = 0;
    } else {
        int gp = batch[i - 1];
        if (gp != g) { gstart[g] = i; gend[gp] = i - 1; }
    }
    if (i == n - 1) gend[g] = n - 1;
}

// --- 3-phase exclusive prefix scan of deg -> rowstart (CSR offsets) ---

__global__ void scan_partial(const int* __restrict__ deg, int* __restrict__ bsum, int n) {
    __shared__ int sh[256];
    int t = threadIdx.x, i = blockIdx.x * 256 + t;
    sh[t] = (i < n) ? deg[i] : 0;
    __syncthreads();
    for (int off = 128; off > 0; off >>= 1) {
        if (t < off) sh[t] += sh[t + off];
        __syncthreads();
    }
    if (t == 0) bsum[blockIdx.x] = sh[0];
}

__global__ void scan_offsets(const int* __restrict__ bsum, int* __restrict__ boff,
                             int* __restrict__ rowstart) {
    __shared__ int sh[256];
    int t = threadIdx.x;
    int v = (t < SCAN_NB) ? bsum[t] : 0;
    sh[t] = v;
    __syncthreads();
    for (int off = 1; off < 256; off <<= 1) {
        int x = (t >= off) ? sh[t - off] : 0;
        __syncthreads();
        sh[t] += x;
        __syncthreads();
    }
    if (t < SCAN_NB) boff[t] = sh[t] - v;
    if (t == 0) rowstart[N_NODES] = N_EDGES;
}

__global__ void scan_write(const int* __restrict__ deg, const int* __restrict__ boff,
                           int* __restrict__ rowstart, int* __restrict__ cursor, int n) {
    __shared__ int sh[256];
    int t = threadIdx.x, i = blockIdx.x * 256 + t;
    int v = (i < n) ? deg[i] : 0;
    sh[t] = v;
    __syncthreads();
    for (int off = 1; off < 256; off <<= 1) {
        int x = (t >= off) ? sh[t - off] : 0;
        __syncthreads();
        sh[t] += x;
        __syncthreads();
    }
    if (i < n) {
        int r = boff[blockIdx.x] + sh[t] - v;
        rowstart[i] = r;
        cursor[i] = r;
    }
}

// bucket edges by dst: e_src[pos] = src (order within bucket is atomic-timed; fp-sum noise only)
__global__ void scatter_kernel(const int* __restrict__ src, const int* __restrict__ dst,
                               int* __restrict__ cursor, int* __restrict__ e_src, int nE) {
    int e = blockIdx.x * blockDim.x + threadIdx.x;
    if (e < nE) {
        int pos = atomicAdd(&cursor[dst[e]], 1);
        e_src[pos] = src[e];
    }
}

// ---------- compute ----------

// H[n][c] = sum_k Xeff[n][k] * W[k][c]; Xeff optionally = relu(X*gA+gB) (fused GraphNorm apply)
// block: (96, 4); each y-slice handles 16 nodes staged in LDS
template <int K, bool PRENORM>
__global__ void gemm_kernel(const float* __restrict__ X, const float* __restrict__ W,
                            float* __restrict__ H, const int* __restrict__ batch,
                            const float* __restrict__ gA, const float* __restrict__ gB) {
    __shared__ float xs[4][16][K];
    int y = threadIdx.y;
    int tid = threadIdx.x;       // 0..95
    int n0 = (blockIdx.x * 4 + y) * 16;

    for (int idx = tid; idx < 16 * K; idx += 96) {
        int r = idx / K, col = idx % K;
        int n = n0 + r;
        float v = 0.f;
        if (n < N_NODES) {
            v = X[(size_t)n * K + col];
            if (PRENORM) {
                int g = batch[n];
                v = fmaxf(fmaf(v, gA[g * HID + col], gB[g * HID + col]), 0.f);
            }
        }
        xs[y][r][col] = v;
    }
    __syncthreads();

    int c = tid;
    float acc[16];
#pragma unroll
    for (int i = 0; i < 16; ++i) acc[i] = 0.f;

    for (int k = 0; k < K; ++k) {
        float w = W[k * HID + c];
#pragma unroll
        for (int i = 0; i < 16; ++i)
            acc[i] = fmaf(xs[y][i][k], w, acc[i]);
    }
#pragma unroll
    for (int i = 0; i < 16; ++i) {
        int n = n0 + i;
        if (n < N_NODES) H[(size_t)n * HID + c] = acc[i];
    }
}

// OUT[n][c] = sum_{in-edges} H[s][c]*dinv[s]*dinv[n] + H[n][c]*dinv[n]^2 + bias[c]
__global__ void agg_kernel(const int* __restrict__ rowstart, const int* __restrict__ e_src,
                           const float* __restrict__ dinv, const float* __restrict__ H,
                           const float* __restrict__ bias, float* __restrict__ OUT) {
    int node = blockIdx.x * 4 + threadIdx.y;
    if (node >= N_NODES) return;
    int c = threadIdx.x;
    int s0 = rowstart[node], s1 = rowstart[node + 1];
    float di = dinv[node];
    float acc = H[(size_t)node * HID + c] * di * di;
    for (int i = s0; i < s1; ++i) {
        int s = e_src[i];
        acc = fmaf(H[(size_t)s * HID + c], dinv[s] * di, acc);
    }
    OUT[(size_t)node * HID + c] = acc + bias[c];
}

// ---------- GraphNorm ----------

__global__ void gn_partial(const float* __restrict__ X, const int* __restrict__ gstart,
                           const int* __restrict__ gend, float* __restrict__ gSum,
                           float* __restrict__ gSq) {
    int g = blockIdx.x, sl = blockIdx.y, c = threadIdx.x;
    int s = gstart[g], e = gend[g];
    if (s > e) return;
    int cnt = e - s + 1;
    int per = (cnt + SLICES - 1) / SLICES;
    int n0 = s + sl * per;
    int n1 = min(n0 + per - 1, e);
    if (n0 > n1) return;
    float sum = 0.f, sq = 0.f;
    for (int n = n0; n <= n1; ++n) {
        float v = X[(size_t)n * HID + c];
        sum += v;
        sq = fmaf(v, v, sq);
    }
    atomicAdd(&gSum[g * HID + c], sum);
    atomicAdd(&gSq[g * HID + c], sq);
}

__global__ void gn_finalize(const float* __restrict__ gSum, const float* __restrict__ gSq,
                            const int* __restrict__ gstart, const int* __restrict__ gend,
                            const float* __restrict__ w, const float* __restrict__ b,
                            const float* __restrict__ a, float* __restrict__ gA,
                            float* __restrict__ gB) {
    int g = blockIdx.x, c = threadIdx.x;
    int s = gstart[g], e = gend[g];
    float A = 0.f, B = 0.f;
    if (s <= e) {
        float cnt = (float)(e - s + 1);
        float mean = gSum[g * HID + c] / cnt;
        float alpha = a[c];
        float var = gSq[g * HID + c] / cnt - (2.f * alpha - alpha * alpha) * mean * mean;
        var = fmaxf(var, 0.f);
        float rs = rsqrtf(var + 1e-5f);
        A = w[c] * rs;
        B = b[c] - alpha * mean * A;
    }
    gA[g * HID + c] = A;
    gB[g * HID + c] = B;
}

// final apply (layer 2): y = relu(x*A[g]+B[g])
__global__ void gn_apply(const float* __restrict__ X, const int* __restrict__ batch,
                         const float* __restrict__ gA, const float* __restrict__ gB,
                         float* __restrict__ Y) {
    int n = blockIdx.x * 4 + threadIdx.y;
    if (n >= N_NODES) return;
    int c = threadIdx.x;
    int g = batch[n];
    float v = fmaf(X[(size_t)n * HID + c], gA[g * HID + c], gB[g * HID + c]);
    Y[(size_t)n * HID + c] = fmaxf(v, 0.f);
}

extern "C" void kernel_launch(void* const* d_in, const int* in_sizes, int n_in,
                              void* d_out, int out_size, void* d_ws, size_t ws_size,
                              hipStream_t stream) {
    const float* x     = (const float*)d_in[0];
    const int*   edge  = (const int*)d_in[1];
    const int*   batch = (const int*)d_in[2];
    const float* W1    = (const float*)d_in[3];
    const float* b1    = (const float*)d_in[4];
    const float* gn1_w = (const float*)d_in[5];
    const float* gn1_b = (const float*)d_in[6];
    const float* gn1_a = (const float*)d_in[7];
    const float* W2    = (const float*)d_in[8];
    const float* b2    = (const float*)d_in[9];
    const float* gn2_w = (const float*)d_in[10];
    const float* gn2_b = (const float*)d_in[11];
    const float* gn2_a = (const float*)d_in[12];
    float* out = (float*)d_out;

    const int* srcv = edge;
    const int* dstv = edge + N_EDGES;

    float* ws   = (float*)d_ws;
    float* dinv = ws;                                   // 50048
    float* bufA = dinv + 50048;                         // 4,800,000 (H)
    float* bufB = bufA + (size_t)N_NODES * HID;         // 4,800,000
    float* gSum = bufB + (size_t)N_NODES * HID;         // 6144
    float* gSq  = gSum + N_GRAPHS * HID;                // 6144
    float* gA   = gSq + N_GRAPHS * HID;                 // 6144
    float* gB   = gA + N_GRAPHS * HID;                  // 6144
    int* deg      = (int*)(gB + N_GRAPHS * HID);        // 50000
    int* rowstart = deg + 50000;                        // 50001 (+pad)
    int* cursor   = rowstart + 50002;                   // 50000
    int* bsum     = cursor + 50000;                     // 200
    int* boff     = bsum + 200;                         // 200
    int* e_src    = boff + 200;                         // 800000
    int* gstart   = e_src + N_EDGES;                    // 64
    int* gend     = gstart + N_GRAPHS;                  // 64

    // ---- preprocessing (once; reused by both layers) ----
    hipMemsetAsync(deg, 0, N_NODES * sizeof(int), stream);
    hipMemsetAsync(gstart, 0x7F, N_GRAPHS * sizeof(int), stream);
    hipMemsetAsync(gend, 0, N_GRAPHS * sizeof(int), stream);

    deg_kernel<<<(N_EDGES + 255) / 256, 256, 0, stream>>>(dstv, deg, N_EDGES);
    dinv_kernel<<<(N_NODES + 255) / 256, 256, 0, stream>>>(deg, dinv, N_NODES);
    bounds_kernel<<<(N_NODES + 255) / 256, 256, 0, stream>>>(batch, gstart, gend, N_NODES);

    scan_partial<<<SCAN_NB, 256, 0, stream>>>(deg, bsum, N_NODES);
    scan_offsets<<<1, 256, 0, stream>>>(bsum, boff, rowstart);
    scan_write<<<SCAN_NB, 256, 0, stream>>>(deg, boff, rowstart, cursor, N_NODES);
    scatter_kernel<<<(N_EDGES + 255) / 256, 256, 0, stream>>>(srcv, dstv, cursor, e_src, N_EDGES);

    const dim3 blk96x4(96, 4);
    const int gemmGrid = (3125 + 3) / 4;   // 50000/16 = 3125 node-tiles, 4 per block
    const int nodeGrid = (N_NODES + 3) / 4;

    // ---------- layer 1 ----------
    gemm_kernel<IN_C, false><<<gemmGrid, blk96x4, 0, stream>>>(x, W1, bufA, nullptr, nullptr, nullptr);
    agg_kernel<<<nodeGrid, blk96x4, 0, stream>>>(rowstart, e_src, dinv, bufA, b1, bufB);
    hipMemsetAsync(gSum, 0, 2 * N_GRAPHS * HID * sizeof(float), stream);
    gn_partial<<<dim3(N_GRAPHS, SLICES), HID, 0, stream>>>(bufB, gstart, gend, gSum, gSq);
    gn_finalize<<<N_GRAPHS, HID, 0, stream>>>(gSum, gSq, gstart, gend, gn1_w, gn1_b, gn1_a, gA, gB);

    // ---------- layer 2 (gn_apply+relu of layer 1 fused into GEMM load) ----------
    gemm_kernel<HID, true><<<gemmGrid, blk96x4, 0, stream>>>(bufB, W2, bufA, batch, gA, gB);
    agg_kernel<<<nodeGrid, blk96x4, 0, stream>>>(rowstart, e_src, dinv, bufA, b2, out);
    hipMemsetAsync(gSum, 0, 2 * N_GRAPHS * HID * sizeof(float), stream);
    gn_partial<<<dim3(N_GRAPHS, SLICES), HID, 0, stream>>>(out, gstart, gend, gSum, gSq);
    gn_finalize<<<N_GRAPHS, HID, 0, stream>>>(gSum, gSq, gstart, gend, gn2_w, gn2_b, gn2_a, gA, gB);
    gn_apply<<<nodeGrid, blk96x4, 0, stream>>>(out, batch, gA, gB, out);
}

// Round 5
// 370.201 us; speedup vs baseline: 3.3028x; 1.4996x over previous
//
#include <hip/hip_runtime.h>
#include <hip/hip_bf16.h>

#define N_NODES 50000
#define N_EDGES 800000
#define N_GRAPHS 64
#define IN_C 128
#define HID 96
#define HID4 24
#define SLICES 8
#define SCAN_NB ((N_NODES + 255) / 256)   // 196

// ---------- preprocessing ----------

__global__ void deg_kernel(const int* __restrict__ dst, int* __restrict__ deg, int nE) {
    int e = blockIdx.x * blockDim.x + threadIdx.x;
    if (e < nE) atomicAdd(&deg[dst[e]], 1);
}

__global__ void dinv_kernel(const int* __restrict__ deg, float* __restrict__ dinv, int n) {
    int i = blockIdx.x * blockDim.x + threadIdx.x;
    if (i < n) dinv[i] = rsqrtf((float)deg[i] + 1.0f);
}

__global__ void bounds_kernel(const int* __restrict__ batch, int* __restrict__ gstart,
                              int* __restrict__ gend, int n) {
    int i = blockIdx.x * blockDim.x + threadIdx.x;
    if (i >= n) return;
    int g = batch[i];
    if (i == 0) {
        gstart[g] = 0;
    } else {
        int gp = batch[i - 1];
        if (gp != g) { gstart[g] = i; gend[gp] = i - 1; }
    }
    if (i == n - 1) gend[g] = n - 1;
}

// --- 3-phase exclusive prefix scan of deg -> rowstart (CSR offsets) ---

__global__ void scan_partial(const int* __restrict__ deg, int* __restrict__ bsum, int n) {
    __shared__ int sh[256];
    int t = threadIdx.x, i = blockIdx.x * 256 + t;
    sh[t] = (i < n) ? deg[i] : 0;
    __syncthreads();
    for (int off = 128; off > 0; off >>= 1) {
        if (t < off) sh[t] += sh[t + off];
        __syncthreads();
    }
    if (t == 0) bsum[blockIdx.x] = sh[0];
}

__global__ void scan_offsets(const int* __restrict__ bsum, int* __restrict__ boff,
                             int* __restrict__ rowstart) {
    __shared__ int sh[256];
    int t = threadIdx.x;
    int v = (t < SCAN_NB) ? bsum[t] : 0;
    sh[t] = v;
    __syncthreads();
    for (int off = 1; off < 256; off <<= 1) {
        int x = (t >= off) ? sh[t - off] : 0;
        __syncthreads();
        sh[t] += x;
        __syncthreads();
    }
    if (t < SCAN_NB) boff[t] = sh[t] - v;
    if (t == 0) rowstart[N_NODES] = N_EDGES;
}

__global__ void scan_write(const int* __restrict__ deg, const int* __restrict__ boff,
                           int* __restrict__ rowstart, int* __restrict__ cursor, int n) {
    __shared__ int sh[256];
    int t = threadIdx.x, i = blockIdx.x * 256 + t;
    int v = (i < n) ? deg[i] : 0;
    sh[t] = v;
    __syncthreads();
    for (int off = 1; off < 256; off <<= 1) {
        int x = (t >= off) ? sh[t - off] : 0;
        __syncthreads();
        sh[t] += x;
        __syncthreads();
    }
    if (i < n) {
        int r = boff[blockIdx.x] + sh[t] - v;
        rowstart[i] = r;
        cursor[i] = r;
    }
}

__global__ void scatter_kernel(const int* __restrict__ src, const int* __restrict__ dst,
                               int* __restrict__ cursor, int* __restrict__ e_src, int nE) {
    int e = blockIdx.x * blockDim.x + threadIdx.x;
    if (e < nE) {
        int pos = atomicAdd(&cursor[dst[e]], 1);
        e_src[pos] = src[e];
    }
}

// ---------- compute ----------

// H[n][c] = sum_k Xeff[n][k] * W[k][c]; Xeff optionally = relu(X*gA+gB)
// block: (96, 4); each y-slice handles 16 nodes staged in LDS (float4 staging loads)
template <int K, bool PRENORM>
__global__ void gemm_kernel(const float* __restrict__ X, const float* __restrict__ W,
                            float* __restrict__ H, const int* __restrict__ batch,
                            const float* __restrict__ gA, const float* __restrict__ gB) {
    __shared__ float xs[4][16][K];
    int y = threadIdx.y;
    int tid = threadIdx.x;       // 0..95
    int n0 = (blockIdx.x * 4 + y) * 16;

    constexpr int K4 = K / 4;
    const float4* X4 = (const float4*)X;
    for (int idx = tid; idx < 16 * K4; idx += 96) {
        int r = idx / K4, q = idx % K4;
        int n = n0 + r;
        float4 v = make_float4(0.f, 0.f, 0.f, 0.f);
        if (n < N_NODES) {
            v = X4[(size_t)n * K4 + q];
            if (PRENORM) {
                int g = batch[n];
                const float4 a4 = ((const float4*)(gA + g * HID))[q];
                const float4 b4 = ((const float4*)(gB + g * HID))[q];
                v.x = fmaxf(fmaf(v.x, a4.x, b4.x), 0.f);
                v.y = fmaxf(fmaf(v.y, a4.y, b4.y), 0.f);
                v.z = fmaxf(fmaf(v.z, a4.z, b4.z), 0.f);
                v.w = fmaxf(fmaf(v.w, a4.w, b4.w), 0.f);
            }
        }
        *reinterpret_cast<float4*>(&xs[y][r][q * 4]) = v;
    }
    __syncthreads();

    int c = tid;
    float acc[16];
#pragma unroll
    for (int i = 0; i < 16; ++i) acc[i] = 0.f;

    for (int k = 0; k < K; ++k) {
        float w = W[k * HID + c];
#pragma unroll
        for (int i = 0; i < 16; ++i)
            acc[i] = fmaf(xs[y][i][k], w, acc[i]);
    }
#pragma unroll
    for (int i = 0; i < 16; ++i) {
        int n = n0 + i;
        if (n < N_NODES) H[(size_t)n * HID + c] = acc[i];
    }
}

// OUT[n][c] = sum_{in-edges} H[s][c]*dinv[s]*dinv[n] + H[n][c]*dinv[n]^2 + bias[c]
// block (24,16): 16 nodes/block, each thread owns 4 channels; unroll-2 for MLP
__global__ void agg_kernel(const int* __restrict__ rowstart, const int* __restrict__ e_src,
                           const float* __restrict__ dinv, const float* __restrict__ H,
                           const float* __restrict__ bias, float* __restrict__ OUT) {
    int node = blockIdx.x * 16 + threadIdx.y;
    if (node >= N_NODES) return;
    int x = threadIdx.x;   // 0..23
    const float4* H4 = (const float4*)H;
    float di = dinv[node];
    int s0 = rowstart[node], s1 = rowstart[node + 1];

    float4 h = H4[(size_t)node * HID4 + x];
    float sw = di * di;
    float4 acc = make_float4(h.x * sw, h.y * sw, h.z * sw, h.w * sw);

    int i = s0;
    for (; i + 2 <= s1; i += 2) {
        int sA = e_src[i], sB = e_src[i + 1];
        float wA = dinv[sA] * di, wB = dinv[sB] * di;
        float4 a4 = H4[(size_t)sA * HID4 + x];
        float4 b4 = H4[(size_t)sB * HID4 + x];
        acc.x = fmaf(a4.x, wA, acc.x); acc.y = fmaf(a4.y, wA, acc.y);
        acc.z = fmaf(a4.z, wA, acc.z); acc.w = fmaf(a4.w, wA, acc.w);
        acc.x = fmaf(b4.x, wB, acc.x); acc.y = fmaf(b4.y, wB, acc.y);
        acc.z = fmaf(b4.z, wB, acc.z); acc.w = fmaf(b4.w, wB, acc.w);
    }
    if (i < s1) {
        int sA = e_src[i];
        float wA = dinv[sA] * di;
        float4 a4 = H4[(size_t)sA * HID4 + x];
        acc.x = fmaf(a4.x, wA, acc.x); acc.y = fmaf(a4.y, wA, acc.y);
        acc.z = fmaf(a4.z, wA, acc.z); acc.w = fmaf(a4.w, wA, acc.w);
    }
    float4 bb = ((const float4*)bias)[x];
    acc.x += bb.x; acc.y += bb.y; acc.z += bb.z; acc.w += bb.w;
    ((float4*)OUT)[(size_t)node * HID4 + x] = acc;
}

// ---------- GraphNorm ----------

__global__ void gn_partial(const float* __restrict__ X, const int* __restrict__ gstart,
                           const int* __restrict__ gend, float* __restrict__ gSum,
                           float* __restrict__ gSq) {
    int g = blockIdx.x, sl = blockIdx.y, c = threadIdx.x;
    int s = gstart[g], e = gend[g];
    if (s > e) return;
    int cnt = e - s + 1;
    int per = (cnt + SLICES - 1) / SLICES;
    int n0 = s + sl * per;
    int n1 = min(n0 + per - 1, e);
    if (n0 > n1) return;
    float sum = 0.f, sq = 0.f;
    for (int n = n0; n <= n1; ++n) {
        float v = X[(size_t)n * HID + c];
        sum += v;
        sq = fmaf(v, v, sq);
    }
    atomicAdd(&gSum[g * HID + c], sum);
    atomicAdd(&gSq[g * HID + c], sq);
}

__global__ void gn_finalize(const float* __restrict__ gSum, const float* __restrict__ gSq,
                            const int* __restrict__ gstart, const int* __restrict__ gend,
                            const float* __restrict__ w, const float* __restrict__ b,
                            const float* __restrict__ a, float* __restrict__ gA,
                            float* __restrict__ gB) {
    int g = blockIdx.x, c = threadIdx.x;
    int s = gstart[g], e = gend[g];
    float A = 0.f, B = 0.f;
    if (s <= e) {
        float cnt = (float)(e - s + 1);
        float mean = gSum[g * HID + c] / cnt;
        float alpha = a[c];
        float var = gSq[g * HID + c] / cnt - (2.f * alpha - alpha * alpha) * mean * mean;
        var = fmaxf(var, 0.f);
        float rs = rsqrtf(var + 1e-5f);
        A = w[c] * rs;
        B = b[c] - alpha * mean * A;
    }
    gA[g * HID + c] = A;
    gB[g * HID + c] = B;
}

// final apply: y = relu(x*A[g]+B[g])  (float4, block (24,16))
__global__ void gn_apply(const float* __restrict__ X, const int* __restrict__ batch,
                         const float* __restrict__ gA, const float* __restrict__ gB,
                         float* __restrict__ Y) {
    int n = blockIdx.x * 16 + threadIdx.y;
    if (n >= N_NODES) return;
    int x = threadIdx.x;
    int g = batch[n];
    float4 v = ((const float4*)X)[(size_t)n * HID4 + x];
    float4 a4 = ((const float4*)(gA + g * HID))[x];
    float4 b4 = ((const float4*)(gB + g * HID))[x];
    v.x = fmaxf(fmaf(v.x, a4.x, b4.x), 0.f);
    v.y = fmaxf(fmaf(v.y, a4.y, b4.y), 0.f);
    v.z = fmaxf(fmaf(v.z, a4.z, b4.z), 0.f);
    v.w = fmaxf(fmaf(v.w, a4.w, b4.w), 0.f);
    ((float4*)Y)[(size_t)n * HID4 + x] = v;
}

extern "C" void kernel_launch(void* const* d_in, const int* in_sizes, int n_in,
                              void* d_out, int out_size, void* d_ws, size_t ws_size,
                              hipStream_t stream) {
    const float* x     = (const float*)d_in[0];
    const int*   edge  = (const int*)d_in[1];
    const int*   batch = (const int*)d_in[2];
    const float* W1    = (const float*)d_in[3];
    const float* b1    = (const float*)d_in[4];
    const float* gn1_w = (const float*)d_in[5];
    const float* gn1_b = (const float*)d_in[6];
    const float* gn1_a = (const float*)d_in[7];
    const float* W2    = (const float*)d_in[8];
    const float* b2    = (const float*)d_in[9];
    const float* gn2_w = (const float*)d_in[10];
    const float* gn2_b = (const float*)d_in[11];
    const float* gn2_a = (const float*)d_in[12];
    float* out = (float*)d_out;

    const int* srcv = edge;
    const int* dstv = edge + N_EDGES;

    float* ws   = (float*)d_ws;
    float* dinv = ws;                                   // 50048
    float* bufA = dinv + 50048;                         // 4,800,000 (H)
    float* bufB = bufA + (size_t)N_NODES * HID;         // 4,800,000
    float* gSum = bufB + (size_t)N_NODES * HID;         // 6144
    float* gSq  = gSum + N_GRAPHS * HID;                // 6144
    float* gA   = gSq + N_GRAPHS * HID;                 // 6144
    float* gB   = gA + N_GRAPHS * HID;                  // 6144
    int* deg      = (int*)(gB + N_GRAPHS * HID);        // 50000
    int* rowstart = deg + 50000;                        // 50001 (+pad)
    int* cursor   = rowstart + 50002;                   // 50000
    int* bsum     = cursor + 50000;                     // 200
    int* boff     = bsum + 200;                         // 200
    int* e_src    = boff + 200;                         // 800000
    int* gstart   = e_src + N_EDGES;                    // 64
    int* gend     = gstart + N_GRAPHS;                  // 64

    // ---- preprocessing (once; reused by both layers) ----
    hipMemsetAsync(deg, 0, N_NODES * sizeof(int), stream);
    hipMemsetAsync(gstart, 0x7F, N_GRAPHS * sizeof(int), stream);
    hipMemsetAsync(gend, 0, N_GRAPHS * sizeof(int), stream);

    deg_kernel<<<(N_EDGES + 255) / 256, 256, 0, stream>>>(dstv, deg, N_EDGES);
    dinv_kernel<<<(N_NODES + 255) / 256, 256, 0, stream>>>(deg, dinv, N_NODES);
    bounds_kernel<<<(N_NODES + 255) / 256, 256, 0, stream>>>(batch, gstart, gend, N_NODES);

    scan_partial<<<SCAN_NB, 256, 0, stream>>>(deg, bsum, N_NODES);
    scan_offsets<<<1, 256, 0, stream>>>(bsum, boff, rowstart);
    scan_write<<<SCAN_NB, 256, 0, stream>>>(deg, boff, rowstart, cursor, N_NODES);
    scatter_kernel<<<(N_EDGES + 255) / 256, 256, 0, stream>>>(srcv, dstv, cursor, e_src, N_EDGES);

    const dim3 blk96x4(96, 4);
    const dim3 blk24x16(24, 16);
    const int gemmGrid = (3125 + 3) / 4;   // 50000/16 node-tiles, 4 per block
    const int nodeGrid16 = (N_NODES + 15) / 16;

    // ---------- layer 1 ----------
    gemm_kernel<IN_C, false><<<gemmGrid, blk96x4, 0, stream>>>(x, W1, bufA, nullptr, nullptr, nullptr);
    agg_kernel<<<nodeGrid16, blk24x16, 0, stream>>>(rowstart, e_src, dinv, bufA, b1, bufB);
    hipMemsetAsync(gSum, 0, 2 * N_GRAPHS * HID * sizeof(float), stream);
    gn_partial<<<dim3(N_GRAPHS, SLICES), HID, 0, stream>>>(bufB, gstart, gend, gSum, gSq);
    gn_finalize<<<N_GRAPHS, HID, 0, stream>>>(gSum, gSq, gstart, gend, gn1_w, gn1_b, gn1_a, gA, gB);

    // ---------- layer 2 (gn_apply+relu of layer 1 fused into GEMM load) ----------
    gemm_kernel<HID, true><<<gemmGrid, blk96x4, 0, stream>>>(bufB, W2, bufA, batch, gA, gB);
    agg_kernel<<<nodeGrid16, blk24x16, 0, stream>>>(rowstart, e_src, dinv, bufA, b2, out);
    hipMemsetAsync(gSum, 0, 2 * N_GRAPHS * HID * sizeof(float), stream);
    gn_partial<<<dim3(N_GRAPHS, SLICES), HID, 0, stream>>>(out, gstart, gend, gSum, gSq);
    gn_finalize<<<N_GRAPHS, HID, 0, stream>>>(gSum, gSq, gstart, gend, gn2_w, gn2_b, gn2_a, gA, gB);
    gn_apply<<<nodeGrid16, blk24x16, 0, stream>>>(out, batch, gA, gB, out);
}

// Round 6
// 232.113 us; speedup vs baseline: 5.2677x; 1.5949x over previous
//
#include <hip/hip_runtime.h>
#include <hip/hip_bf16.h>

#define N_NODES 50000
#define N_EDGES 800000
#define N_GRAPHS 64
#define IN_C 128
#define HID 96
#define SLICES 8
#define SCAN_NB ((N_NODES + 255) / 256)   // 196

typedef short s16x8 __attribute__((ext_vector_type(8)));
typedef float f32x4 __attribute__((ext_vector_type(4)));

__device__ inline unsigned short f2bf(float f) {
    union { __hip_bfloat16 b; unsigned short u; } cv;
    cv.b = __float2bfloat16(f);
    return cv.u;
}
__device__ inline float bf2f(unsigned short u) { return __uint_as_float((unsigned int)u << 16); }
__device__ inline float bf_lo(unsigned int u) { return __uint_as_float(u << 16); }
__device__ inline float bf_hi(unsigned int u) { return __uint_as_float(u & 0xffff0000u); }

// ---------- preprocessing ----------

__global__ void deg_kernel(const int* __restrict__ dst, int* __restrict__ deg, int nE) {
    int e = blockIdx.x * blockDim.x + threadIdx.x;
    if (e < nE) atomicAdd(&deg[dst[e]], 1);
}

__global__ void dinv_kernel(const int* __restrict__ deg, float* __restrict__ dinv, int n) {
    int i = blockIdx.x * blockDim.x + threadIdx.x;
    if (i < n) dinv[i] = rsqrtf((float)deg[i] + 1.0f);
}

__global__ void bounds_kernel(const int* __restrict__ batch, int* __restrict__ gstart,
                              int* __restrict__ gend, int n) {
    int i = blockIdx.x * blockDim.x + threadIdx.x;
    if (i >= n) return;
    int g = batch[i];
    if (i == 0) {
        gstart[g] = 0;
    } else {
        int gp = batch[i - 1];
        if (gp != g) { gstart[g] = i; gend[gp] = i - 1; }
    }
    if (i == n - 1) gend[g] = n - 1;
}

__global__ void scan_partial(const int* __restrict__ deg, int* __restrict__ bsum, int n) {
    __shared__ int sh[256];
    int t = threadIdx.x, i = blockIdx.x * 256 + t;
    sh[t] = (i < n) ? deg[i] : 0;
    __syncthreads();
    for (int off = 128; off > 0; off >>= 1) {
        if (t < off) sh[t] += sh[t + off];
        __syncthreads();
    }
    if (t == 0) bsum[blockIdx.x] = sh[0];
}

__global__ void scan_offsets(const int* __restrict__ bsum, int* __restrict__ boff,
                             int* __restrict__ rowstart) {
    __shared__ int sh[256];
    int t = threadIdx.x;
    int v = (t < SCAN_NB) ? bsum[t] : 0;
    sh[t] = v;
    __syncthreads();
    for (int off = 1; off < 256; off <<= 1) {
        int x = (t >= off) ? sh[t - off] : 0;
        __syncthreads();
        sh[t] += x;
        __syncthreads();
    }
    if (t < SCAN_NB) boff[t] = sh[t] - v;
    if (t == 0) rowstart[N_NODES] = N_EDGES;
}

__global__ void scan_write(const int* __restrict__ deg, const int* __restrict__ boff,
                           int* __restrict__ rowstart, int* __restrict__ cursor, int n) {
    __shared__ int sh[256];
    int t = threadIdx.x, i = blockIdx.x * 256 + t;
    int v = (i < n) ? deg[i] : 0;
    sh[t] = v;
    __syncthreads();
    for (int off = 1; off < 256; off <<= 1) {
        int x = (t >= off) ? sh[t - off] : 0;
        __syncthreads();
        sh[t] += x;
        __syncthreads();
    }
    if (i < n) {
        int r = boff[blockIdx.x] + sh[t] - v;
        rowstart[i] = r;
        cursor[i] = r;
    }
}

__global__ void scatter_kernel(const int* __restrict__ src, const int* __restrict__ dst,
                               int* __restrict__ cursor, int* __restrict__ e_src, int nE) {
    int e = blockIdx.x * blockDim.x + threadIdx.x;
    if (e < nE) {
        int pos = atomicAdd(&cursor[dst[e]], 1);
        e_src[pos] = src[e];
    }
}

// ---------- MFMA GEMM ----------
// OUT tile per wave: 16 rows x 96 cols via 6x 16x16x32 bf16 MFMA per k-step.
// Epilogue scales row by dinv[row] and stores bf16 (H' = H * dinv).
// PRENORM (layer 2): A = relu(X_bf16 * gA[g] + gB[g]) fused into A-frag load.
template <int K, bool PRENORM>
__global__ __launch_bounds__(256)
void gemm_mfma(const void* __restrict__ Xv, const float* __restrict__ W,
               const float* __restrict__ dinv, const int* __restrict__ batch,
               const float* __restrict__ gA, const float* __restrict__ gB,
               unsigned short* __restrict__ Hp) {
    constexpr int KP = K + 8;     // padded LDS stride (2-way conflict only)
    constexpr int KS = K / 32;    // k-steps
    __shared__ unsigned short Wt[96 * KP];  // Wt[c][k] = bf16(W[k][c])
    int tid = threadIdx.x;
    for (int idx = tid; idx < K * 96; idx += 256) {
        int k = idx / 96, c = idx - k * 96;
        Wt[c * KP + k] = f2bf(W[idx]);
    }
    __syncthreads();

    const int lane = tid & 63;
    const int quad = lane >> 4;   // 0..3
    const int l16 = lane & 15;

    // B-frags in registers, loaded once: lane holds B[k = s*32+quad*8+j][col = t*16+l16]
    s16x8 Bf[6][KS];
#pragma unroll
    for (int t = 0; t < 6; ++t)
#pragma unroll
        for (int s = 0; s < KS; ++s)
            Bf[t][s] = *(const s16x8*)&Wt[(t * 16 + l16) * KP + s * 32 + quad * 8];

    int gw = blockIdx.x * 4 + (tid >> 6);
    int nw = gridDim.x * 4;
    for (int tile = gw; tile < N_NODES / 16; tile += nw) {
        int n0 = tile * 16;
        int row = n0 + l16;
        // A-frags: lane holds A[row = l16][k = s*32+quad*8+j]
        s16x8 Af[KS];
        if (!PRENORM) {
            const float* Xr = (const float*)Xv + (size_t)row * K;
#pragma unroll
            for (int s = 0; s < KS; ++s) {
                int k0 = s * 32 + quad * 8;
                float4 u = *(const float4*)(Xr + k0);
                float4 v = *(const float4*)(Xr + k0 + 4);
                s16x8 a;
                a[0] = (short)f2bf(u.x); a[1] = (short)f2bf(u.y);
                a[2] = (short)f2bf(u.z); a[3] = (short)f2bf(u.w);
                a[4] = (short)f2bf(v.x); a[5] = (short)f2bf(v.y);
                a[6] = (short)f2bf(v.z); a[7] = (short)f2bf(v.w);
                Af[s] = a;
            }
        } else {
            const unsigned short* Xr = (const unsigned short*)Xv + (size_t)row * HID;
            int g = batch[row];
            const float* ga = gA + g * HID;
            const float* gb = gB + g * HID;
#pragma unroll
            for (int s = 0; s < KS; ++s) {
                int k0 = s * 32 + quad * 8;
                uint4 raw = *(const uint4*)(Xr + k0);
                float4 a0 = *(const float4*)(ga + k0);
                float4 a1 = *(const float4*)(ga + k0 + 4);
                float4 b0 = *(const float4*)(gb + k0);
                float4 b1 = *(const float4*)(gb + k0 + 4);
                s16x8 a;
                a[0] = (short)f2bf(fmaxf(fmaf(bf_lo(raw.x), a0.x, b0.x), 0.f));
                a[1] = (short)f2bf(fmaxf(fmaf(bf_hi(raw.x), a0.y, b0.y), 0.f));
                a[2] = (short)f2bf(fmaxf(fmaf(bf_lo(raw.y), a0.z, b0.z), 0.f));
                a[3] = (short)f2bf(fmaxf(fmaf(bf_hi(raw.y), a0.w, b0.w), 0.f));
                a[4] = (short)f2bf(fmaxf(fmaf(bf_lo(raw.z), a1.x, b1.x), 0.f));
                a[5] = (short)f2bf(fmaxf(fmaf(bf_hi(raw.z), a1.y, b1.y), 0.f));
                a[6] = (short)f2bf(fmaxf(fmaf(bf_lo(raw.w), a1.z, b1.z), 0.f));
                a[7] = (short)f2bf(fmaxf(fmaf(bf_hi(raw.w), a1.w, b1.w), 0.f));
                Af[s] = a;
            }
        }
        f32x4 acc[6];
#pragma unroll
        for (int t = 0; t < 6; ++t) { acc[t][0] = 0.f; acc[t][1] = 0.f; acc[t][2] = 0.f; acc[t][3] = 0.f; }
#pragma unroll
        for (int s = 0; s < KS; ++s)
#pragma unroll
            for (int t = 0; t < 6; ++t)
                acc[t] = __builtin_amdgcn_mfma_f32_16x16x32_bf16(Af[s], Bf[t][s], acc[t], 0, 0, 0);

        // C/D: col = t*16 + l16, row = n0 + quad*4 + r
        float4 dv = *(const float4*)(dinv + n0 + quad * 4);
#pragma unroll
        for (int t = 0; t < 6; ++t) {
            size_t base = (size_t)(n0 + quad * 4) * HID + t * 16 + l16;
            Hp[base]            = f2bf(acc[t][0] * dv.x);
            Hp[base + HID]      = f2bf(acc[t][1] * dv.y);
            Hp[base + 2 * HID]  = f2bf(acc[t][2] * dv.z);
            Hp[base + 3 * HID]  = f2bf(acc[t][3] * dv.w);
        }
    }
}

// ---------- aggregation (bf16 gather, no per-edge dinv) ----------
// OUT[n] = dinv[n] * (sum_{s in in(n)} H'[s] + H'[n]) + bias
__global__ __launch_bounds__(384)
void agg_kernel(const int* __restrict__ rowstart, const int* __restrict__ e_src,
                const float* __restrict__ dinv, const unsigned short* __restrict__ H,
                const float* __restrict__ bias, unsigned short* __restrict__ OUT) {
    int node = blockIdx.x * 16 + threadIdx.y;
    int x = threadIdx.x;   // 0..23 (4 channels each)
    const ushort4* H4 = (const ushort4*)H;
    size_t ridx = (size_t)node * 24 + x;
    ushort4 hv = H4[ridx];
    float ax = bf2f(hv.x), ay = bf2f(hv.y), az = bf2f(hv.z), aw = bf2f(hv.w);
    int s0 = rowstart[node], s1 = rowstart[node + 1];
    int i = s0;
    for (; i + 2 <= s1; i += 2) {
        int sA = e_src[i], sB = e_src[i + 1];
        ushort4 a4 = H4[(size_t)sA * 24 + x];
        ushort4 b4 = H4[(size_t)sB * 24 + x];
        ax += bf2f(a4.x); ay += bf2f(a4.y); az += bf2f(a4.z); aw += bf2f(a4.w);
        ax += bf2f(b4.x); ay += bf2f(b4.y); az += bf2f(b4.z); aw += bf2f(b4.w);
    }
    if (i < s1) {
        int sA = e_src[i];
        ushort4 a4 = H4[(size_t)sA * 24 + x];
        ax += bf2f(a4.x); ay += bf2f(a4.y); az += bf2f(a4.z); aw += bf2f(a4.w);
    }
    float di = dinv[node];
    float4 bb = ((const float4*)bias)[x];
    ushort4 ov;
    ov.x = f2bf(fmaf(ax, di, bb.x));
    ov.y = f2bf(fmaf(ay, di, bb.y));
    ov.z = f2bf(fmaf(az, di, bb.z));
    ov.w = f2bf(fmaf(aw, di, bb.w));
    ((ushort4*)OUT)[ridx] = ov;
}

// ---------- GraphNorm ----------

__global__ __launch_bounds__(768)
void gn_partial(const unsigned short* __restrict__ Xb, const int* __restrict__ gstart,
                const int* __restrict__ gend, float* __restrict__ gSum, float* __restrict__ gSq) {
    __shared__ float4 sSum[32][24];
    __shared__ float4 sSq[32][24];
    int g = blockIdx.x, sl = blockIdx.y;
    int x = threadIdx.x, ty = threadIdx.y;
    int s = gstart[g], e = gend[g];
    float sx = 0, sy = 0, sz = 0, sw = 0, qx = 0, qy = 0, qz = 0, qw = 0;
    if (s <= e) {
        int cnt = e - s + 1;
        int per = (cnt + SLICES - 1) / SLICES;
        int n0 = s + sl * per;
        int n1 = min(n0 + per - 1, e);
        const ushort4* X4 = (const ushort4*)Xb;
        for (int n = n0 + ty; n <= n1; n += 32) {
            ushort4 h = X4[(size_t)n * 24 + x];
            float vx = bf2f(h.x), vy = bf2f(h.y), vz = bf2f(h.z), vw = bf2f(h.w);
            sx += vx; qx = fmaf(vx, vx, qx);
            sy += vy; qy = fmaf(vy, vy, qy);
            sz += vz; qz = fmaf(vz, vz, qz);
            sw += vw; qw = fmaf(vw, vw, qw);
        }
    }
    sSum[ty][x] = make_float4(sx, sy, sz, sw);
    sSq[ty][x] = make_float4(qx, qy, qz, qw);
    __syncthreads();
    for (int off = 16; off > 0; off >>= 1) {
        if (ty < off) {
            float4 a = sSum[ty + off][x], b = sSum[ty][x];
            sSum[ty][x] = make_float4(a.x + b.x, a.y + b.y, a.z + b.z, a.w + b.w);
            float4 c = sSq[ty + off][x], d = sSq[ty][x];
            sSq[ty][x] = make_float4(c.x + d.x, c.y + d.y, c.z + d.z, c.w + d.w);
        }
        __syncthreads();
    }
    if (ty == 0 && s <= e) {
        float4 S = sSum[0][x], Q = sSq[0][x];
        atomicAdd(&gSum[g * HID + x * 4 + 0], S.x);
        atomicAdd(&gSum[g * HID + x * 4 + 1], S.y);
        atomicAdd(&gSum[g * HID + x * 4 + 2], S.z);
        atomicAdd(&gSum[g * HID + x * 4 + 3], S.w);
        atomicAdd(&gSq[g * HID + x * 4 + 0], Q.x);
        atomicAdd(&gSq[g * HID + x * 4 + 1], Q.y);
        atomicAdd(&gSq[g * HID + x * 4 + 2], Q.z);
        atomicAdd(&gSq[g * HID + x * 4 + 3], Q.w);
    }
}

__global__ void gn_finalize(const float* __restrict__ gSum, const float* __restrict__ gSq,
                            const int* __restrict__ gstart, const int* __restrict__ gend,
                            const float* __restrict__ w, const float* __restrict__ b,
                            const float* __restrict__ a, float* __restrict__ gA,
                            float* __restrict__ gB) {
    int g = blockIdx.x, c = threadIdx.x;
    int s = gstart[g], e = gend[g];
    float A = 0.f, B = 0.f;
    if (s <= e) {
        float cnt = (float)(e - s + 1);
        float mean = gSum[g * HID + c] / cnt;
        float alpha = a[c];
        float var = gSq[g * HID + c] / cnt - (2.f * alpha - alpha * alpha) * mean * mean;
        var = fmaxf(var, 0.f);
        float rs = rsqrtf(var + 1e-5f);
        A = w[c] * rs;
        B = b[c] - alpha * mean * A;
    }
    gA[g * HID + c] = A;
    gB[g * HID + c] = B;
}

// final apply: d_out(f32) = relu(bf16(X)*A[g]+B[g])
__global__ void gn_apply(const unsigned short* __restrict__ Xb, const int* __restrict__ batch,
                         const float* __restrict__ gA, const float* __restrict__ gB,
                         float* __restrict__ Y) {
    int n = blockIdx.x * 16 + threadIdx.y;
    int x = threadIdx.x;
    int g = batch[n];
    ushort4 h = ((const ushort4*)Xb)[(size_t)n * 24 + x];
    float4 a4 = ((const float4*)(gA + g * HID))[x];
    float4 b4 = ((const float4*)(gB + g * HID))[x];
    float4 v;
    v.x = fmaxf(fmaf(bf2f(h.x), a4.x, b4.x), 0.f);
    v.y = fmaxf(fmaf(bf2f(h.y), a4.y, b4.y), 0.f);
    v.z = fmaxf(fmaf(bf2f(h.z), a4.z, b4.z), 0.f);
    v.w = fmaxf(fmaf(bf2f(h.w), a4.w, b4.w), 0.f);
    ((float4*)Y)[(size_t)n * 24 + x] = v;
}

extern "C" void kernel_launch(void* const* d_in, const int* in_sizes, int n_in,
                              void* d_out, int out_size, void* d_ws, size_t ws_size,
                              hipStream_t stream) {
    const float* x     = (const float*)d_in[0];
    const int*   edge  = (const int*)d_in[1];
    const int*   batch = (const int*)d_in[2];
    const float* W1    = (const float*)d_in[3];
    const float* b1    = (const float*)d_in[4];
    const float* gn1_w = (const float*)d_in[5];
    const float* gn1_b = (const float*)d_in[6];
    const float* gn1_a = (const float*)d_in[7];
    const float* W2    = (const float*)d_in[8];
    const float* b2    = (const float*)d_in[9];
    const float* gn2_w = (const float*)d_in[10];
    const float* gn2_b = (const float*)d_in[11];
    const float* gn2_a = (const float*)d_in[12];
    float* out = (float*)d_out;

    const int* srcv = edge;
    const int* dstv = edge + N_EDGES;

    float* ws   = (float*)d_ws;
    float* dinv = ws;                         // 50048 f
    float* gSum = dinv + 50048;               // 6144 f
    float* gSq  = gSum + 6144;                // 6144 f
    float* gA   = gSq + 6144;                 // 6144 f
    float* gB   = gA + 6144;                  // 6144 f
    int* deg      = (int*)(gB + 6144);        // 50000
    int* rowstart = deg + 50000;              // 50008 (padded)
    int* cursor   = rowstart + 50008;         // 50000
    int* bsum     = cursor + 50000;           // 200
    int* boff     = bsum + 200;               // 200
    int* gstart   = boff + 200;               // 64
    int* gend     = gstart + 64;              // 64
    int* e_src    = gend + 64;                // 800000
    unsigned short* Hbf = (unsigned short*)(e_src + N_EDGES);   // 4.8M bf16
    unsigned short* Obf = Hbf + (size_t)N_NODES * HID;          // 4.8M bf16

    // ---- preprocessing (once; reused by both layers) ----
    hipMemsetAsync(deg, 0, N_NODES * sizeof(int), stream);
    hipMemsetAsync(gstart, 0x7F, N_GRAPHS * sizeof(int), stream);
    hipMemsetAsync(gend, 0, N_GRAPHS * sizeof(int), stream);

    deg_kernel<<<(N_EDGES + 255) / 256, 256, 0, stream>>>(dstv, deg, N_EDGES);
    dinv_kernel<<<(N_NODES + 255) / 256, 256, 0, stream>>>(deg, dinv, N_NODES);
    bounds_kernel<<<(N_NODES + 255) / 256, 256, 0, stream>>>(batch, gstart, gend, N_NODES);

    scan_partial<<<SCAN_NB, 256, 0, stream>>>(deg, bsum, N_NODES);
    scan_offsets<<<1, 256, 0, stream>>>(bsum, boff, rowstart);
    scan_write<<<SCAN_NB, 256, 0, stream>>>(deg, boff, rowstart, cursor, N_NODES);
    scatter_kernel<<<(N_EDGES + 255) / 256, 256, 0, stream>>>(srcv, dstv, cursor, e_src, N_EDGES);

    const dim3 blk24x16(24, 16);
    const dim3 blk24x32(24, 32);
    const int nodeGrid16 = N_NODES / 16;   // 3125 exact

    // ---------- layer 1 ----------
    gemm_mfma<IN_C, false><<<256, 256, 0, stream>>>(x, W1, dinv, nullptr, nullptr, nullptr, Hbf);
    agg_kernel<<<nodeGrid16, blk24x16, 0, stream>>>(rowstart, e_src, dinv, Hbf, b1, Obf);
    hipMemsetAsync(gSum, 0, 2 * 6144 * sizeof(float), stream);
    gn_partial<<<dim3(N_GRAPHS, SLICES), blk24x32, 0, stream>>>(Obf, gstart, gend, gSum, gSq);
    gn_finalize<<<N_GRAPHS, HID, 0, stream>>>(gSum, gSq, gstart, gend, gn1_w, gn1_b, gn1_a, gA, gB);

    // ---------- layer 2 (gn_apply+relu fused into A-frag load) ----------
    gemm_mfma<HID, true><<<256, 256, 0, stream>>>(Obf, W2, dinv, batch, gA, gB, Hbf);
    agg_kernel<<<nodeGrid16, blk24x16, 0, stream>>>(rowstart, e_src, dinv, Hbf, b2, Obf);
    hipMemsetAsync(gSum, 0, 2 * 6144 * sizeof(float), stream);
    gn_partial<<<dim3(N_GRAPHS, SLICES), blk24x32, 0, stream>>>(Obf, gstart, gend, gSum, gSq);
    gn_finalize<<<N_GRAPHS, HID, 0, stream>>>(gSum, gSq, gstart, gend, gn2_w, gn2_b, gn2_a, gA, gB);
    gn_apply<<<nodeGrid16, blk24x16, 0, stream>>>(Obf, batch, gA, gB, out);
}

// Round 7
// 169.965 us; speedup vs baseline: 7.1938x; 1.3657x over previous
//
#include <hip/hip_runtime.h>
#include <hip/hip_bf16.h>

#define N_NODES 50000
#define N_EDGES 800000
#define N_GRAPHS 64
#define IN_C 128
#define HID 96
#define SLICES 8
#define NBUCK 196      // node buckets of 256 nodes
#define NCHK 200       // edge chunks
#define EPC 4000       // edges per chunk (NCHK*EPC == N_EDGES)

typedef short s16x8 __attribute__((ext_vector_type(8)));
typedef float f32x4 __attribute__((ext_vector_type(4)));

__device__ inline unsigned short f2bf(float f) {
    union { __hip_bfloat16 b; unsigned short u; } cv;
    cv.b = __float2bfloat16(f);
    return cv.u;
}
__device__ inline float bf2f(unsigned short u) { return __uint_as_float((unsigned int)u << 16); }
__device__ inline float bf_lo(unsigned int u) { return __uint_as_float(u << 16); }
__device__ inline float bf_hi(unsigned int u) { return __uint_as_float(u & 0xffff0000u); }

// ---------- preprocessing ----------

__global__ void bounds_kernel(const int* __restrict__ batch, int* __restrict__ gstart,
                              int* __restrict__ gend, int n) {
    int i = blockIdx.x * blockDim.x + threadIdx.x;
    if (i >= n) return;
    int g = batch[i];
    if (i == 0) {
        gstart[g] = 0;
    } else {
        int gp = batch[i - 1];
        if (gp != g) { gstart[g] = i; gend[gp] = i - 1; }
    }
    if (i == n - 1) gend[g] = n - 1;
}

// P1: per-chunk histogram over coarse buckets (dst>>8)
__global__ __launch_bounds__(256)
void p1_hist(const int* __restrict__ dst, int* __restrict__ chunkHist) {
    __shared__ int h[NBUCK];
    int c = blockIdx.x, t = threadIdx.x;
    for (int i = t; i < NBUCK; i += 256) h[i] = 0;
    __syncthreads();
    int base = c * EPC;
    for (int i = t; i < EPC; i += 256)
        atomicAdd(&h[dst[base + i] >> 8], 1);
    __syncthreads();
    for (int i = t; i < NBUCK; i += 256) chunkHist[c * NBUCK + i] = h[i];
}

// P2: bucketBase (exclusive scan of bucket totals) + per-(chunk,bucket) window offsets
__global__ __launch_bounds__(256)
void p2_offsets(const int* __restrict__ chunkHist, int* __restrict__ offTab,
                int* __restrict__ bucketBase, int* __restrict__ rowstart) {
    __shared__ int sh[256];
    int t = threadIdx.x;
    int tot = 0;
    if (t < NBUCK)
        for (int c = 0; c < NCHK; ++c) tot += chunkHist[c * NBUCK + t];
    sh[t] = (t < NBUCK) ? tot : 0;
    __syncthreads();
    for (int off = 1; off < 256; off <<= 1) {
        int x = (t >= off) ? sh[t - off] : 0;
        __syncthreads();
        sh[t] += x;
        __syncthreads();
    }
    if (t < NBUCK) {
        int bb = sh[t] - tot;   // exclusive
        bucketBase[t] = bb;
        int run = bb;
        for (int c = 0; c < NCHK; ++c) {
            offTab[c * NBUCK + t] = run;
            run += chunkHist[c * NBUCK + t];
        }
    }
    if (t == 0) { bucketBase[NBUCK] = N_EDGES; rowstart[N_NODES] = N_EDGES; }
}

// P3: place packed (fine<<16 | src) into per-chunk windows (each line ~one block)
__global__ __launch_bounds__(256)
void p3_place(const int* __restrict__ src, const int* __restrict__ dst,
              const int* __restrict__ offTab, unsigned int* __restrict__ epacked) {
    __shared__ int cur[NBUCK];
    int c = blockIdx.x, t = threadIdx.x;
    for (int i = t; i < NBUCK; i += 256) cur[i] = offTab[c * NBUCK + i];
    __syncthreads();
    int base = c * EPC;
    for (int i = t; i < EPC; i += 256) {
        int d = dst[base + i];
        int s = src[base + i];
        int pos = atomicAdd(&cur[d >> 8], 1);
        epacked[pos] = ((unsigned)(d & 255) << 16) | (unsigned)s;
    }
}

// P4: per-bucket fine counting sort -> rowstart, dinv, u16 src list (all writes coalesced)
__global__ __launch_bounds__(256)
void p4_fine(const unsigned int* __restrict__ epacked, const int* __restrict__ bucketBase,
             int* __restrict__ rowstart, float* __restrict__ dinv,
             unsigned short* __restrict__ e_src16) {
    __shared__ int h[256];
    __shared__ int rs[256];
    __shared__ unsigned short sorted[8192];
    int b = blockIdx.x, t = threadIdx.x;
    int s0 = bucketBase[b], len = bucketBase[b + 1] - s0;
    h[t] = 0;
    __syncthreads();
    for (int i = t; i < len; i += 256)
        atomicAdd(&h[(epacked[s0 + i] >> 16) & 255], 1);
    __syncthreads();
    int deg = h[t];
    int v = deg;
    rs[t] = v;
    __syncthreads();
    for (int off = 1; off < 256; off <<= 1) {
        int x = (t >= off) ? rs[t - off] : 0;
        __syncthreads();
        rs[t] += x;
        __syncthreads();
    }
    int myrow = rs[t] - deg;   // exclusive local offset
    int node = b * 256 + t;
    if (node < N_NODES) {
        rowstart[node] = s0 + myrow;
        dinv[node] = rsqrtf((float)deg + 1.0f);
    }
    __syncthreads();
    h[t] = myrow;              // reuse as cursor
    __syncthreads();
    for (int i = t; i < len; i += 256) {
        unsigned int p = epacked[s0 + i];
        int pos = atomicAdd(&h[(p >> 16) & 255], 1);
        sorted[pos] = (unsigned short)(p & 0xffffu);
    }
    __syncthreads();
    for (int i = t; i < len; i += 256) e_src16[s0 + i] = sorted[i];
}

// ---------- MFMA GEMM ----------
template <int K, bool PRENORM>
__global__ __launch_bounds__(256)
void gemm_mfma(const void* __restrict__ Xv, const float* __restrict__ W,
               const float* __restrict__ dinv, const int* __restrict__ batch,
               const float* __restrict__ gA, const float* __restrict__ gB,
               unsigned short* __restrict__ Hp) {
    constexpr int KP = K + 8;
    constexpr int KS = K / 32;
    __shared__ unsigned short Wt[96 * KP];
    int tid = threadIdx.x;
    for (int idx = tid; idx < K * 96; idx += 256) {
        int k = idx / 96, c = idx - k * 96;
        Wt[c * KP + k] = f2bf(W[idx]);
    }
    __syncthreads();

    const int lane = tid & 63;
    const int quad = lane >> 4;
    const int l16 = lane & 15;

    s16x8 Bf[6][KS];
#pragma unroll
    for (int t = 0; t < 6; ++t)
#pragma unroll
        for (int s = 0; s < KS; ++s)
            Bf[t][s] = *(const s16x8*)&Wt[(t * 16 + l16) * KP + s * 32 + quad * 8];

    int gw = blockIdx.x * 4 + (tid >> 6);
    int nw = gridDim.x * 4;
    for (int tile = gw; tile < N_NODES / 16; tile += nw) {
        int n0 = tile * 16;
        int row = n0 + l16;
        s16x8 Af[KS];
        if (!PRENORM) {
            const float* Xr = (const float*)Xv + (size_t)row * K;
#pragma unroll
            for (int s = 0; s < KS; ++s) {
                int k0 = s * 32 + quad * 8;
                float4 u = *(const float4*)(Xr + k0);
                float4 v = *(const float4*)(Xr + k0 + 4);
                s16x8 a;
                a[0] = (short)f2bf(u.x); a[1] = (short)f2bf(u.y);
                a[2] = (short)f2bf(u.z); a[3] = (short)f2bf(u.w);
                a[4] = (short)f2bf(v.x); a[5] = (short)f2bf(v.y);
                a[6] = (short)f2bf(v.z); a[7] = (short)f2bf(v.w);
                Af[s] = a;
            }
        } else {
            const unsigned short* Xr = (const unsigned short*)Xv + (size_t)row * HID;
            int g = batch[row];
            const float* ga = gA + g * HID;
            const float* gb = gB + g * HID;
#pragma unroll
            for (int s = 0; s < KS; ++s) {
                int k0 = s * 32 + quad * 8;
                uint4 raw = *(const uint4*)(Xr + k0);
                float4 a0 = *(const float4*)(ga + k0);
                float4 a1 = *(const float4*)(ga + k0 + 4);
                float4 b0 = *(const float4*)(gb + k0);
                float4 b1 = *(const float4*)(gb + k0 + 4);
                s16x8 a;
                a[0] = (short)f2bf(fmaxf(fmaf(bf_lo(raw.x), a0.x, b0.x), 0.f));
                a[1] = (short)f2bf(fmaxf(fmaf(bf_hi(raw.x), a0.y, b0.y), 0.f));
                a[2] = (short)f2bf(fmaxf(fmaf(bf_lo(raw.y), a0.z, b0.z), 0.f));
                a[3] = (short)f2bf(fmaxf(fmaf(bf_hi(raw.y), a0.w, b0.w), 0.f));
                a[4] = (short)f2bf(fmaxf(fmaf(bf_lo(raw.z), a1.x, b1.x), 0.f));
                a[5] = (short)f2bf(fmaxf(fmaf(bf_hi(raw.z), a1.y, b1.y), 0.f));
                a[6] = (short)f2bf(fmaxf(fmaf(bf_lo(raw.w), a1.z, b1.z), 0.f));
                a[7] = (short)f2bf(fmaxf(fmaf(bf_hi(raw.w), a1.w, b1.w), 0.f));
                Af[s] = a;
            }
        }
        f32x4 acc[6];
#pragma unroll
        for (int t = 0; t < 6; ++t) { acc[t][0] = 0.f; acc[t][1] = 0.f; acc[t][2] = 0.f; acc[t][3] = 0.f; }
#pragma unroll
        for (int s = 0; s < KS; ++s)
#pragma unroll
            for (int t = 0; t < 6; ++t)
                acc[t] = __builtin_amdgcn_mfma_f32_16x16x32_bf16(Af[s], Bf[t][s], acc[t], 0, 0, 0);

        float4 dv = *(const float4*)(dinv + n0 + quad * 4);
#pragma unroll
        for (int t = 0; t < 6; ++t) {
            size_t base = (size_t)(n0 + quad * 4) * HID + t * 16 + l16;
            Hp[base]            = f2bf(acc[t][0] * dv.x);
            Hp[base + HID]      = f2bf(acc[t][1] * dv.y);
            Hp[base + 2 * HID]  = f2bf(acc[t][2] * dv.z);
            Hp[base + 3 * HID]  = f2bf(acc[t][3] * dv.w);
        }
    }
}

// ---------- aggregation (bf16 gather, u16 edge list) ----------
__global__ __launch_bounds__(384)
void agg_kernel(const int* __restrict__ rowstart, const unsigned short* __restrict__ e_src,
                const float* __restrict__ dinv, const unsigned short* __restrict__ H,
                const float* __restrict__ bias, unsigned short* __restrict__ OUT) {
    int node = blockIdx.x * 16 + threadIdx.y;
    int x = threadIdx.x;
    const ushort4* H4 = (const ushort4*)H;
    size_t ridx = (size_t)node * 24 + x;
    ushort4 hv = H4[ridx];
    float ax = bf2f(hv.x), ay = bf2f(hv.y), az = bf2f(hv.z), aw = bf2f(hv.w);
    int s0 = rowstart[node], s1 = rowstart[node + 1];
    int i = s0;
    for (; i + 2 <= s1; i += 2) {
        int sA = e_src[i], sB = e_src[i + 1];
        ushort4 a4 = H4[(size_t)sA * 24 + x];
        ushort4 b4 = H4[(size_t)sB * 24 + x];
        ax += bf2f(a4.x); ay += bf2f(a4.y); az += bf2f(a4.z); aw += bf2f(a4.w);
        ax += bf2f(b4.x); ay += bf2f(b4.y); az += bf2f(b4.z); aw += bf2f(b4.w);
    }
    if (i < s1) {
        int sA = e_src[i];
        ushort4 a4 = H4[(size_t)sA * 24 + x];
        ax += bf2f(a4.x); ay += bf2f(a4.y); az += bf2f(a4.z); aw += bf2f(a4.w);
    }
    float di = dinv[node];
    float4 bb = ((const float4*)bias)[x];
    ushort4 ov;
    ov.x = f2bf(fmaf(ax, di, bb.x));
    ov.y = f2bf(fmaf(ay, di, bb.y));
    ov.z = f2bf(fmaf(az, di, bb.z));
    ov.w = f2bf(fmaf(aw, di, bb.w));
    ((ushort4*)OUT)[ridx] = ov;
}

// ---------- GraphNorm ----------

__global__ __launch_bounds__(768)
void gn_partial(const unsigned short* __restrict__ Xb, const int* __restrict__ gstart,
                const int* __restrict__ gend, float* __restrict__ gSum, float* __restrict__ gSq) {
    __shared__ float4 sSum[32][24];
    __shared__ float4 sSq[32][24];
    int g = blockIdx.x, sl = blockIdx.y;
    int x = threadIdx.x, ty = threadIdx.y;
    int s = gstart[g], e = gend[g];
    float sx = 0, sy = 0, sz = 0, sw = 0, qx = 0, qy = 0, qz = 0, qw = 0;
    if (s <= e) {
        int cnt = e - s + 1;
        int per = (cnt + SLICES - 1) / SLICES;
        int n0 = s + sl * per;
        int n1 = min(n0 + per - 1, e);
        const ushort4* X4 = (const ushort4*)Xb;
        for (int n = n0 + ty; n <= n1; n += 32) {
            ushort4 h = X4[(size_t)n * 24 + x];
            float vx = bf2f(h.x), vy = bf2f(h.y), vz = bf2f(h.z), vw = bf2f(h.w);
            sx += vx; qx = fmaf(vx, vx, qx);
            sy += vy; qy = fmaf(vy, vy, qy);
            sz += vz; qz = fmaf(vz, vz, qz);
            sw += vw; qw = fmaf(vw, vw, qw);
        }
    }
    sSum[ty][x] = make_float4(sx, sy, sz, sw);
    sSq[ty][x] = make_float4(qx, qy, qz, qw);
    __syncthreads();
    for (int off = 16; off > 0; off >>= 1) {
        if (ty < off) {
            float4 a = sSum[ty + off][x], b = sSum[ty][x];
            sSum[ty][x] = make_float4(a.x + b.x, a.y + b.y, a.z + b.z, a.w + b.w);
            float4 c = sSq[ty + off][x], d = sSq[ty][x];
            sSq[ty][x] = make_float4(c.x + d.x, c.y + d.y, c.z + d.z, c.w + d.w);
        }
        __syncthreads();
    }
    if (ty == 0 && s <= e) {
        float4 S = sSum[0][x], Q = sSq[0][x];
        atomicAdd(&gSum[g * HID + x * 4 + 0], S.x);
        atomicAdd(&gSum[g * HID + x * 4 + 1], S.y);
        atomicAdd(&gSum[g * HID + x * 4 + 2], S.z);
        atomicAdd(&gSum[g * HID + x * 4 + 3], S.w);
        atomicAdd(&gSq[g * HID + x * 4 + 0], Q.x);
        atomicAdd(&gSq[g * HID + x * 4 + 1], Q.y);
        atomicAdd(&gSq[g * HID + x * 4 + 2], Q.z);
        atomicAdd(&gSq[g * HID + x * 4 + 3], Q.w);
    }
}

__global__ void gn_finalize(const float* __restrict__ gSum, const float* __restrict__ gSq,
                            const int* __restrict__ gstart, const int* __restrict__ gend,
                            const float* __restrict__ w, const float* __restrict__ b,
                            const float* __restrict__ a, float* __restrict__ gA,
                            float* __restrict__ gB) {
    int g = blockIdx.x, c = threadIdx.x;
    int s = gstart[g], e = gend[g];
    float A = 0.f, B = 0.f;
    if (s <= e) {
        float cnt = (float)(e - s + 1);
        float mean = gSum[g * HID + c] / cnt;
        float alpha = a[c];
        float var = gSq[g * HID + c] / cnt - (2.f * alpha - alpha * alpha) * mean * mean;
        var = fmaxf(var, 0.f);
        float rs = rsqrtf(var + 1e-5f);
        A = w[c] * rs;
        B = b[c] - alpha * mean * A;
    }
    gA[g * HID + c] = A;
    gB[g * HID + c] = B;
}

__global__ void gn_apply(const unsigned short* __restrict__ Xb, const int* __restrict__ batch,
                         const float* __restrict__ gA, const float* __restrict__ gB,
                         float* __restrict__ Y) {
    int n = blockIdx.x * 16 + threadIdx.y;
    int x = threadIdx.x;
    int g = batch[n];
    ushort4 h = ((const ushort4*)Xb)[(size_t)n * 24 + x];
    float4 a4 = ((const float4*)(gA + g * HID))[x];
    float4 b4 = ((const float4*)(gB + g * HID))[x];
    float4 v;
    v.x = fmaxf(fmaf(bf2f(h.x), a4.x, b4.x), 0.f);
    v.y = fmaxf(fmaf(bf2f(h.y), a4.y, b4.y), 0.f);
    v.z = fmaxf(fmaf(bf2f(h.z), a4.z, b4.z), 0.f);
    v.w = fmaxf(fmaf(bf2f(h.w), a4.w, b4.w), 0.f);
    ((float4*)Y)[(size_t)n * 24 + x] = v;
}

extern "C" void kernel_launch(void* const* d_in, const int* in_sizes, int n_in,
                              void* d_out, int out_size, void* d_ws, size_t ws_size,
                              hipStream_t stream) {
    const float* x     = (const float*)d_in[0];
    const int*   edge  = (const int*)d_in[1];
    const int*   batch = (const int*)d_in[2];
    const float* W1    = (const float*)d_in[3];
    const float* b1    = (const float*)d_in[4];
    const float* gn1_w = (const float*)d_in[5];
    const float* gn1_b = (const float*)d_in[6];
    const float* gn1_a = (const float*)d_in[7];
    const float* W2    = (const float*)d_in[8];
    const float* b2    = (const float*)d_in[9];
    const float* gn2_w = (const float*)d_in[10];
    const float* gn2_b = (const float*)d_in[11];
    const float* gn2_a = (const float*)d_in[12];
    float* out = (float*)d_out;

    const int* srcv = edge;
    const int* dstv = edge + N_EDGES;

    float* ws   = (float*)d_ws;
    float* dinv = ws;                          // 50048 f
    float* gSum = dinv + 50048;                // 6144 f
    float* gSq  = gSum + 6144;                 // 6144 f
    float* gA   = gSq + 6144;                  // 6144 f
    float* gB   = gA + 6144;                   // 6144 f
    int* rowstart   = (int*)(gB + 6144);       // 50008
    int* chunkHist  = rowstart + 50008;        // 39200
    int* offTab     = chunkHist + NCHK * NBUCK;// 39200
    int* bucketBase = offTab + NCHK * NBUCK;   // 200 (padded)
    int* gstart     = bucketBase + 200;        // 64
    int* gend       = gstart + 64;             // 64
    unsigned int* epacked = (unsigned int*)(gend + 64);           // 800000 u32
    unsigned short* e_src16 = (unsigned short*)(epacked + N_EDGES); // 800000 u16
    unsigned short* Hbf = e_src16 + N_EDGES;                      // 4.8M bf16
    unsigned short* Obf = Hbf + (size_t)N_NODES * HID;            // 4.8M bf16

    // ---- preprocessing (once; reused by both layers) ----
    hipMemsetAsync(gstart, 0x7F, N_GRAPHS * sizeof(int), stream);
    hipMemsetAsync(gend, 0, N_GRAPHS * sizeof(int), stream);

    bounds_kernel<<<(N_NODES + 255) / 256, 256, 0, stream>>>(batch, gstart, gend, N_NODES);
    p1_hist<<<NCHK, 256, 0, stream>>>(dstv, chunkHist);
    p2_offsets<<<1, 256, 0, stream>>>(chunkHist, offTab, bucketBase, rowstart);
    p3_place<<<NCHK, 256, 0, stream>>>(srcv, dstv, offTab, epacked);
    p4_fine<<<NBUCK, 256, 0, stream>>>(epacked, bucketBase, rowstart, dinv, e_src16);

    const dim3 blk24x16(24, 16);
    const dim3 blk24x32(24, 32);
    const int nodeGrid16 = N_NODES / 16;   // 3125 exact

    // ---------- layer 1 ----------
    gemm_mfma<IN_C, false><<<256, 256, 0, stream>>>(x, W1, dinv, nullptr, nullptr, nullptr, Hbf);
    agg_kernel<<<nodeGrid16, blk24x16, 0, stream>>>(rowstart, e_src16, dinv, Hbf, b1, Obf);
    hipMemsetAsync(gSum, 0, 2 * 6144 * sizeof(float), stream);
    gn_partial<<<dim3(N_GRAPHS, SLICES), blk24x32, 0, stream>>>(Obf, gstart, gend, gSum, gSq);
    gn_finalize<<<N_GRAPHS, HID, 0, stream>>>(gSum, gSq, gstart, gend, gn1_w, gn1_b, gn1_a, gA, gB);

    // ---------- layer 2 (gn_apply+relu fused into A-frag load) ----------
    gemm_mfma<HID, true><<<256, 256, 0, stream>>>(Obf, W2, dinv, batch, gA, gB, Hbf);
    agg_kernel<<<nodeGrid16, blk24x16, 0, stream>>>(rowstart, e_src16, dinv, Hbf, b2, Obf);
    hipMemsetAsync(gSum, 0, 2 * 6144 * sizeof(float), stream);
    gn_partial<<<dim3(N_GRAPHS, SLICES), blk24x32, 0, stream>>>(Obf, gstart, gend, gSum, gSq);
    gn_finalize<<<N_GRAPHS, HID, 0, stream>>>(gSum, gSq, gstart, gend, gn2_w, gn2_b, gn2_a, gA, gB);
    gn_apply<<<nodeGrid16, blk24x16, 0, stream>>>(Obf, batch, gA, gB, out);
}

// Round 8
// 153.724 us; speedup vs baseline: 7.9539x; 1.1057x over previous
//
#include <hip/hip_runtime.h>
#include <hip/hip_bf16.h>

#define N_NODES 50000
#define N_EDGES 800000
#define N_GRAPHS 64
#define IN_C 128
#define HID 96
#define SLICES 8
#define NBUCK 196      // node buckets of 256 nodes
#define NCHK 200       // edge chunks
#define EPC 4000       // edges per chunk (NCHK*EPC == N_EDGES)

typedef short s16x8 __attribute__((ext_vector_type(8)));
typedef float f32x4 __attribute__((ext_vector_type(4)));

__device__ inline unsigned short f2bf(float f) {
    union { __hip_bfloat16 b; unsigned short u; } cv;
    cv.b = __float2bfloat16(f);
    return cv.u;
}
__device__ inline float bf2f(unsigned short u) { return __uint_as_float((unsigned int)u << 16); }
__device__ inline float bf_lo(unsigned int u) { return __uint_as_float(u << 16); }
__device__ inline float bf_hi(unsigned int u) { return __uint_as_float(u & 0xffff0000u); }
__device__ inline unsigned int pack2(float lo, float hi) {
    return (unsigned)f2bf(lo) | ((unsigned)f2bf(hi) << 16);
}
__device__ inline void acc8(float* a, uint4 r) {
    a[0] += bf_lo(r.x); a[1] += bf_hi(r.x);
    a[2] += bf_lo(r.y); a[3] += bf_hi(r.y);
    a[4] += bf_lo(r.z); a[5] += bf_hi(r.z);
    a[6] += bf_lo(r.w); a[7] += bf_hi(r.w);
}

// ---------- preprocessing ----------

// P1: per-chunk coarse histogram (dst>>8) + graph bounds (batch sorted)
__global__ __launch_bounds__(256)
void p1_hist(const int* __restrict__ dst, int* __restrict__ chunkHist,
             const int* __restrict__ batch, int* __restrict__ gstart, int* __restrict__ gend) {
    __shared__ int h[NBUCK];
    int c = blockIdx.x, t = threadIdx.x;
    for (int i = t; i < NBUCK; i += 256) h[i] = 0;
    __syncthreads();
    int base = c * EPC;
    for (int i = t; i < EPC; i += 256)
        atomicAdd(&h[dst[base + i] >> 8], 1);
    __syncthreads();
    for (int i = t; i < NBUCK; i += 256) chunkHist[c * NBUCK + i] = h[i];

    int gi = c * 256 + t;
    if (gi < N_NODES) {
        int g = batch[gi];
        if (gi == 0) {
            gstart[g] = 0;
        } else {
            int gp = batch[gi - 1];
            if (gp != g) { gstart[g] = gi; gend[gp] = gi - 1; }
        }
        if (gi == N_NODES - 1) gend[g] = N_NODES - 1;
    }
}

// P2a: per-bucket exclusive scan over 200 chunks -> offTabRel, bucketTot
__global__ __launch_bounds__(256)
void p2a_scan(const int* __restrict__ chunkHist, int* __restrict__ offTabRel,
              int* __restrict__ bucketTot) {
    __shared__ int sh[256];
    __shared__ int hv[256];
    int b = blockIdx.x, t = threadIdx.x;
    int v = (t < NCHK) ? chunkHist[t * NBUCK + b] : 0;
    hv[t] = v;
    sh[t] = v;
    __syncthreads();
    for (int off = 1; off < 256; off <<= 1) {
        int x = (t >= off) ? sh[t - off] : 0;
        __syncthreads();
        sh[t] += x;
        __syncthreads();
    }
    if (t < NCHK) offTabRel[t * NBUCK + b] = sh[t] - hv[t];
    if (t == 255) bucketTot[b] = sh[255];
}

// P2b: scan of 196 bucket totals -> bucketBase
__global__ __launch_bounds__(256)
void p2b_base(const int* __restrict__ bucketTot, int* __restrict__ bucketBase,
              int* __restrict__ rowstart) {
    __shared__ int sh[256];
    int t = threadIdx.x;
    int v = (t < NBUCK) ? bucketTot[t] : 0;
    sh[t] = v;
    __syncthreads();
    for (int off = 1; off < 256; off <<= 1) {
        int x = (t >= off) ? sh[t - off] : 0;
        __syncthreads();
        sh[t] += x;
        __syncthreads();
    }
    if (t < NBUCK) bucketBase[t] = sh[t] - v;
    if (t == 0) { bucketBase[NBUCK] = N_EDGES; rowstart[N_NODES] = N_EDGES; }
}

// P3: place packed (fine<<16 | src) into per-(chunk,bucket) windows
__global__ __launch_bounds__(256)
void p3_place(const int* __restrict__ src, const int* __restrict__ dst,
              const int* __restrict__ offTabRel, const int* __restrict__ bucketBase,
              unsigned int* __restrict__ epacked) {
    __shared__ int cur[NBUCK];
    int c = blockIdx.x, t = threadIdx.x;
    for (int i = t; i < NBUCK; i += 256)
        cur[i] = bucketBase[i] + offTabRel[c * NBUCK + i];
    __syncthreads();
    int base = c * EPC;
    for (int i = t; i < EPC; i += 256) {
        int d = dst[base + i];
        int s = src[base + i];
        int pos = atomicAdd(&cur[d >> 8], 1);
        epacked[pos] = ((unsigned)(d & 255) << 16) | (unsigned)s;
    }
}

// P4: per-bucket fine counting sort -> rowstart, dinv, u16 src list
__global__ __launch_bounds__(256)
void p4_fine(const unsigned int* __restrict__ epacked, const int* __restrict__ bucketBase,
             int* __restrict__ rowstart, float* __restrict__ dinv,
             unsigned short* __restrict__ e_src16) {
    __shared__ int h[256];
    __shared__ int rs[256];
    __shared__ unsigned short sorted[8192];
    int b = blockIdx.x, t = threadIdx.x;
    int s0 = bucketBase[b], len = bucketBase[b + 1] - s0;
    h[t] = 0;
    __syncthreads();
    for (int i = t; i < len; i += 256)
        atomicAdd(&h[(epacked[s0 + i] >> 16) & 255], 1);
    __syncthreads();
    int deg = h[t];
    rs[t] = deg;
    __syncthreads();
    for (int off = 1; off < 256; off <<= 1) {
        int x = (t >= off) ? rs[t - off] : 0;
        __syncthreads();
        rs[t] += x;
        __syncthreads();
    }
    int myrow = rs[t] - deg;
    int node = b * 256 + t;
    if (node < N_NODES) {
        rowstart[node] = s0 + myrow;
        dinv[node] = rsqrtf((float)deg + 1.0f);
    }
    __syncthreads();
    h[t] = myrow;
    __syncthreads();
    for (int i = t; i < len; i += 256) {
        unsigned int p = epacked[s0 + i];
        int pos = atomicAdd(&h[(p >> 16) & 255], 1);
        sorted[pos] = (unsigned short)(p & 0xffffu);
    }
    __syncthreads();
    for (int i = t; i < len; i += 256) e_src16[s0 + i] = sorted[i];
}

// ---------- MFMA GEMM ----------
template <int K, bool PRENORM>
__global__ __launch_bounds__(256)
void gemm_mfma(const void* __restrict__ Xv, const float* __restrict__ W,
               const float* __restrict__ dinv, const int* __restrict__ batch,
               const float* __restrict__ gA, const float* __restrict__ gB,
               unsigned short* __restrict__ Hp) {
    constexpr int KP = K + 8;
    constexpr int KS = K / 32;
    __shared__ unsigned short Wt[96 * KP];
    int tid = threadIdx.x;
    for (int idx = tid; idx < K * 96; idx += 256) {
        int k = idx / 96, c = idx - k * 96;
        Wt[c * KP + k] = f2bf(W[idx]);
    }
    __syncthreads();

    const int lane = tid & 63;
    const int quad = lane >> 4;
    const int l16 = lane & 15;

    s16x8 Bf[6][KS];
#pragma unroll
    for (int t = 0; t < 6; ++t)
#pragma unroll
        for (int s = 0; s < KS; ++s)
            Bf[t][s] = *(const s16x8*)&Wt[(t * 16 + l16) * KP + s * 32 + quad * 8];

    int gw = blockIdx.x * 4 + (tid >> 6);
    int nw = gridDim.x * 4;
    for (int tile = gw; tile < N_NODES / 16; tile += nw) {
        int n0 = tile * 16;
        int row = n0 + l16;
        s16x8 Af[KS];
        if (!PRENORM) {
            const float* Xr = (const float*)Xv + (size_t)row * K;
#pragma unroll
            for (int s = 0; s < KS; ++s) {
                int k0 = s * 32 + quad * 8;
                float4 u = *(const float4*)(Xr + k0);
                float4 v = *(const float4*)(Xr + k0 + 4);
                s16x8 a;
                a[0] = (short)f2bf(u.x); a[1] = (short)f2bf(u.y);
                a[2] = (short)f2bf(u.z); a[3] = (short)f2bf(u.w);
                a[4] = (short)f2bf(v.x); a[5] = (short)f2bf(v.y);
                a[6] = (short)f2bf(v.z); a[7] = (short)f2bf(v.w);
                Af[s] = a;
            }
        } else {
            const unsigned short* Xr = (const unsigned short*)Xv + (size_t)row * HID;
            int g = batch[row];
            const float* ga = gA + g * HID;
            const float* gb = gB + g * HID;
#pragma unroll
            for (int s = 0; s < KS; ++s) {
                int k0 = s * 32 + quad * 8;
                uint4 raw = *(const uint4*)(Xr + k0);
                float4 a0 = *(const float4*)(ga + k0);
                float4 a1 = *(const float4*)(ga + k0 + 4);
                float4 b0 = *(const float4*)(gb + k0);
                float4 b1 = *(const float4*)(gb + k0 + 4);
                s16x8 a;
                a[0] = (short)f2bf(fmaxf(fmaf(bf_lo(raw.x), a0.x, b0.x), 0.f));
                a[1] = (short)f2bf(fmaxf(fmaf(bf_hi(raw.x), a0.y, b0.y), 0.f));
                a[2] = (short)f2bf(fmaxf(fmaf(bf_lo(raw.y), a0.z, b0.z), 0.f));
                a[3] = (short)f2bf(fmaxf(fmaf(bf_hi(raw.y), a0.w, b0.w), 0.f));
                a[4] = (short)f2bf(fmaxf(fmaf(bf_lo(raw.z), a1.x, b1.x), 0.f));
                a[5] = (short)f2bf(fmaxf(fmaf(bf_hi(raw.z), a1.y, b1.y), 0.f));
                a[6] = (short)f2bf(fmaxf(fmaf(bf_lo(raw.w), a1.z, b1.z), 0.f));
                a[7] = (short)f2bf(fmaxf(fmaf(bf_hi(raw.w), a1.w, b1.w), 0.f));
                Af[s] = a;
            }
        }
        f32x4 acc[6];
#pragma unroll
        for (int t = 0; t < 6; ++t) { acc[t][0] = 0.f; acc[t][1] = 0.f; acc[t][2] = 0.f; acc[t][3] = 0.f; }
#pragma unroll
        for (int s = 0; s < KS; ++s)
#pragma unroll
            for (int t = 0; t < 6; ++t)
                acc[t] = __builtin_amdgcn_mfma_f32_16x16x32_bf16(Af[s], Bf[t][s], acc[t], 0, 0, 0);

        float4 dv = *(const float4*)(dinv + n0 + quad * 4);
#pragma unroll
        for (int t = 0; t < 6; ++t) {
            size_t base = (size_t)(n0 + quad * 4) * HID + t * 16 + l16;
            Hp[base]            = f2bf(acc[t][0] * dv.x);
            Hp[base + HID]      = f2bf(acc[t][1] * dv.y);
            Hp[base + 2 * HID]  = f2bf(acc[t][2] * dv.z);
            Hp[base + 3 * HID]  = f2bf(acc[t][3] * dv.w);
        }
    }
}

// ---------- aggregation: block (12,32), 16B rows, unroll 4 ----------
__global__ __launch_bounds__(384)
void agg_kernel(const int* __restrict__ rowstart, const unsigned short* __restrict__ e_src,
                const float* __restrict__ dinv, const unsigned short* __restrict__ H,
                const float* __restrict__ bias, unsigned short* __restrict__ OUT) {
    int node = blockIdx.x * 32 + threadIdx.y;
    if (node >= N_NODES) return;
    int x = threadIdx.x;   // 0..11, 8 channels each
    const uint4* H8 = (const uint4*)H;
    size_t ridx = (size_t)node * 12 + x;
    float a[8] = {0, 0, 0, 0, 0, 0, 0, 0};
    acc8(a, H8[ridx]);   // self contribution (H' already scaled by dinv)
    int s0 = rowstart[node], s1 = rowstart[node + 1];
    int i = s0;
    for (; i + 4 <= s1; i += 4) {
        int sA = e_src[i], sB = e_src[i + 1], sC = e_src[i + 2], sD = e_src[i + 3];
        uint4 rA = H8[(size_t)sA * 12 + x];
        uint4 rB = H8[(size_t)sB * 12 + x];
        uint4 rC = H8[(size_t)sC * 12 + x];
        uint4 rD = H8[(size_t)sD * 12 + x];
        acc8(a, rA); acc8(a, rB); acc8(a, rC); acc8(a, rD);
    }
    for (; i < s1; ++i)
        acc8(a, H8[(size_t)e_src[i] * 12 + x]);

    float di = dinv[node];
    float4 b0 = *(const float4*)(bias + x * 8);
    float4 b1 = *(const float4*)(bias + x * 8 + 4);
    uint4 ov;
    ov.x = pack2(fmaf(a[0], di, b0.x), fmaf(a[1], di, b0.y));
    ov.y = pack2(fmaf(a[2], di, b0.z), fmaf(a[3], di, b0.w));
    ov.z = pack2(fmaf(a[4], di, b1.x), fmaf(a[5], di, b1.y));
    ov.w = pack2(fmaf(a[6], di, b1.z), fmaf(a[7], di, b1.w));
    ((uint4*)OUT)[ridx] = ov;
}

// ---------- GraphNorm: partial sums + last-block finalize ----------
__global__ __launch_bounds__(768)
void gn_partial(const unsigned short* __restrict__ Xb, const int* __restrict__ gstart,
                const int* __restrict__ gend, float* __restrict__ gSum, float* __restrict__ gSq,
                int* __restrict__ done, const float* __restrict__ w, const float* __restrict__ b,
                const float* __restrict__ a, float* __restrict__ gA, float* __restrict__ gB) {
    __shared__ float4 sSum[32][24];
    __shared__ float4 sSq[32][24];
    __shared__ int lastFlag;
    int g = blockIdx.x, sl = blockIdx.y;
    int x = threadIdx.x, ty = threadIdx.y;
    int s = gstart[g], e = gend[g];
    float sx = 0, sy = 0, sz = 0, sw = 0, qx = 0, qy = 0, qz = 0, qw = 0;
    if (s <= e) {
        int cnt = e - s + 1;
        int per = (cnt + SLICES - 1) / SLICES;
        int n0 = s + sl * per;
        int n1 = min(n0 + per - 1, e);
        const ushort4* X4 = (const ushort4*)Xb;
        for (int n = n0 + ty; n <= n1; n += 32) {
            ushort4 h = X4[(size_t)n * 24 + x];
            float vx = bf2f(h.x), vy = bf2f(h.y), vz = bf2f(h.z), vw = bf2f(h.w);
            sx += vx; qx = fmaf(vx, vx, qx);
            sy += vy; qy = fmaf(vy, vy, qy);
            sz += vz; qz = fmaf(vz, vz, qz);
            sw += vw; qw = fmaf(vw, vw, qw);
        }
    }
    sSum[ty][x] = make_float4(sx, sy, sz, sw);
    sSq[ty][x] = make_float4(qx, qy, qz, qw);
    __syncthreads();
    for (int off = 16; off > 0; off >>= 1) {
        if (ty < off) {
            float4 A = sSum[ty + off][x], B = sSum[ty][x];
            sSum[ty][x] = make_float4(A.x + B.x, A.y + B.y, A.z + B.z, A.w + B.w);
            float4 C = sSq[ty + off][x], D = sSq[ty][x];
            sSq[ty][x] = make_float4(C.x + D.x, C.y + D.y, C.z + D.z, C.w + D.w);
        }
        __syncthreads();
    }
    if (ty == 0) {
        float4 S = sSum[0][x], Q = sSq[0][x];
        atomicAdd(&gSum[g * HID + x * 4 + 0], S.x);
        atomicAdd(&gSum[g * HID + x * 4 + 1], S.y);
        atomicAdd(&gSum[g * HID + x * 4 + 2], S.z);
        atomicAdd(&gSum[g * HID + x * 4 + 3], S.w);
        atomicAdd(&gSq[g * HID + x * 4 + 0], Q.x);
        atomicAdd(&gSq[g * HID + x * 4 + 1], Q.y);
        atomicAdd(&gSq[g * HID + x * 4 + 2], Q.z);
        atomicAdd(&gSq[g * HID + x * 4 + 3], Q.w);
        __threadfence();
    }
    __syncthreads();
    if (ty == 0 && x == 0) {
        int old = atomicAdd(&done[g], 1);
        lastFlag = (old == SLICES - 1) ? 1 : 0;
    }
    __syncthreads();
    if (lastFlag) {
        int t = ty * 24 + x;
        if (t < HID) {
            float S = atomicAdd(&gSum[g * HID + t], 0.0f);   // coherent read
            float Q = atomicAdd(&gSq[g * HID + t], 0.0f);
            float A = 0.f, B = 0.f;
            if (s <= e) {
                float cnt = (float)(e - s + 1);
                float mean = S / cnt;
                float alpha = a[t];
                float var = Q / cnt - (2.f * alpha - alpha * alpha) * mean * mean;
                var = fmaxf(var, 0.f);
                float rsv = rsqrtf(var + 1e-5f);
                A = w[t] * rsv;
                B = b[t] - alpha * mean * A;
            }
            gA[g * HID + t] = A;
            gB[g * HID + t] = B;
        }
    }
}

// final apply: d_out(f32) = relu(bf16(X)*A[g]+B[g]); block (12,32)
__global__ __launch_bounds__(384)
void gn_apply(const unsigned short* __restrict__ Xb, const int* __restrict__ batch,
              const float* __restrict__ gA, const float* __restrict__ gB,
              float* __restrict__ Y) {
    int n = blockIdx.x * 32 + threadIdx.y;
    if (n >= N_NODES) return;
    int x = threadIdx.x;
    int g = batch[n];
    uint4 h = ((const uint4*)Xb)[(size_t)n * 12 + x];
    const float* ga = gA + g * HID + x * 8;
    const float* gb = gB + g * HID + x * 8;
    float4 a0 = *(const float4*)ga, a1 = *(const float4*)(ga + 4);
    float4 b0 = *(const float4*)gb, b1 = *(const float4*)(gb + 4);
    float4 o0, o1;
    o0.x = fmaxf(fmaf(bf_lo(h.x), a0.x, b0.x), 0.f);
    o0.y = fmaxf(fmaf(bf_hi(h.x), a0.y, b0.y), 0.f);
    o0.z = fmaxf(fmaf(bf_lo(h.y), a0.z, b0.z), 0.f);
    o0.w = fmaxf(fmaf(bf_hi(h.y), a0.w, b0.w), 0.f);
    o1.x = fmaxf(fmaf(bf_lo(h.z), a1.x, b1.x), 0.f);
    o1.y = fmaxf(fmaf(bf_hi(h.z), a1.y, b1.y), 0.f);
    o1.z = fmaxf(fmaf(bf_lo(h.w), a1.z, b1.z), 0.f);
    o1.w = fmaxf(fmaf(bf_hi(h.w), a1.w, b1.w), 0.f);
    float* yr = Y + (size_t)n * HID + x * 8;
    *(float4*)yr = o0;
    *(float4*)(yr + 4) = o1;
}

extern "C" void kernel_launch(void* const* d_in, const int* in_sizes, int n_in,
                              void* d_out, int out_size, void* d_ws, size_t ws_size,
                              hipStream_t stream) {
    const float* x     = (const float*)d_in[0];
    const int*   edge  = (const int*)d_in[1];
    const int*   batch = (const int*)d_in[2];
    const float* W1    = (const float*)d_in[3];
    const float* b1    = (const float*)d_in[4];
    const float* gn1_w = (const float*)d_in[5];
    const float* gn1_b = (const float*)d_in[6];
    const float* gn1_a = (const float*)d_in[7];
    const float* W2    = (const float*)d_in[8];
    const float* b2    = (const float*)d_in[9];
    const float* gn2_w = (const float*)d_in[10];
    const float* gn2_b = (const float*)d_in[11];
    const float* gn2_a = (const float*)d_in[12];
    float* out = (float*)d_out;

    const int* srcv = edge;
    const int* dstv = edge + N_EDGES;

    float* ws   = (float*)d_ws;
    float* dinv = ws;                          // 50048 f
    float* gA   = dinv + 50048;                // 6144 f
    float* gB   = gA + 6144;                   // 6144 f
    // --- single zero-memset block ---
    float* zb    = gB + 6144;
    float* gSum1 = zb;                         // 6144
    float* gSq1  = gSum1 + 6144;               // 6144
    float* gSum2 = gSq1 + 6144;                // 6144
    float* gSq2  = gSum2 + 6144;               // 6144
    int* done1   = (int*)(gSq2 + 6144);        // 64
    int* done2   = done1 + 64;                 // 64
    int* gstart  = done2 + 64;                 // 64
    int* gend    = gstart + 64;                // 64
    const size_t ZB_BYTES = (4 * 6144 + 4 * 64) * sizeof(float);
    // --- rest ---
    int* rowstart   = gend + 64;               // 50008
    int* chunkHist  = rowstart + 50008;        // 39200
    int* offTabRel  = chunkHist + NCHK * NBUCK;// 39200
    int* bucketTot  = offTabRel + NCHK * NBUCK;// 200 (pad)
    int* bucketBase = bucketTot + 200;         // 200 (pad, 197 used)
    unsigned int* epacked = (unsigned int*)(bucketBase + 200);      // 800000 u32
    unsigned short* e_src16 = (unsigned short*)(epacked + N_EDGES); // 800000 u16
    unsigned short* Hbf = e_src16 + N_EDGES;                        // 4.8M bf16
    unsigned short* Obf = Hbf + (size_t)N_NODES * HID;              // 4.8M bf16

    // ---- preprocessing ----
    hipMemsetAsync(zb, 0, ZB_BYTES, stream);
    p1_hist<<<NCHK, 256, 0, stream>>>(dstv, chunkHist, batch, gstart, gend);
    p2a_scan<<<NBUCK, 256, 0, stream>>>(chunkHist, offTabRel, bucketTot);
    p2b_base<<<1, 256, 0, stream>>>(bucketTot, bucketBase, rowstart);
    p3_place<<<NCHK, 256, 0, stream>>>(srcv, dstv, offTabRel, bucketBase, epacked);
    p4_fine<<<NBUCK, 256, 0, stream>>>(epacked, bucketBase, rowstart, dinv, e_src16);

    const dim3 blk12x32(12, 32);
    const dim3 blk24x32(24, 32);
    const int nodeGrid32 = (N_NODES + 31) / 32;   // 1563

    // ---------- layer 1 ----------
    gemm_mfma<IN_C, false><<<391, 256, 0, stream>>>(x, W1, dinv, nullptr, nullptr, nullptr, Hbf);
    agg_kernel<<<nodeGrid32, blk12x32, 0, stream>>>(rowstart, e_src16, dinv, Hbf, b1, Obf);
    gn_partial<<<dim3(N_GRAPHS, SLICES), blk24x32, 0, stream>>>(Obf, gstart, gend, gSum1, gSq1,
                                                                done1, gn1_w, gn1_b, gn1_a, gA, gB);

    // ---------- layer 2 (gn_apply+relu fused into A-frag load) ----------
    gemm_mfma<HID, true><<<391, 256, 0, stream>>>(Obf, W2, dinv, batch, gA, gB, Hbf);
    agg_kernel<<<nodeGrid32, blk12x32, 0, stream>>>(rowstart, e_src16, dinv, Hbf, b2, Obf);
    gn_partial<<<dim3(N_GRAPHS, SLICES), blk24x32, 0, stream>>>(Obf, gstart, gend, gSum2, gSq2,
                                                                done2, gn2_w, gn2_b, gn2_a, gA, gB);
    gn_apply<<<nodeGrid32, blk12x32, 0, stream>>>(Obf, batch, gA, gB, out);
}